// Round 14
// baseline (546.494 us; speedup 1.0000x reference)
//
#include <hip/hip_runtime.h>
#include <hip/hip_bf16.h>

// LightGCN_27384711480190 — r14: r13 with DETERMINISTIC local_sort
// (wave-serialized leader atomics; edge position = pure function of input).
#define NUQ 100000   // users
#define NIQ 50000    // items
#define NQ  150000   // N = NU + NI
#define DQ  64       // embedding dim (== wavefront)
#define GQ  4        // groups
#define EPSM 1e-2f   // argmax margin; bf16x3 score err ~1e-3 tail

#define SCAN_NB  ((NQ + 255) / 256)
#define SCANB_PER ((SCAN_NB + 63) / 64)
#define PSHIFT 11
#define NPART ((NQ + (1 << PSHIFT) - 1) >> PSHIFT)   // 74 partitions of 2048 rows
#define FRAGU (8 * 64 * 4)                           // uints per fragment block

typedef __attribute__((ext_vector_type(8))) short bf16x8;
typedef __attribute__((ext_vector_type(4))) float f32x4;
typedef __attribute__((ext_vector_type(4))) unsigned int uint4v;

__device__ __forceinline__ unsigned f2bf(float f) {   // RNE f32 -> bf16 bits
    unsigned u = __float_as_uint(f);
    return (u + 0x7FFFu + ((u >> 16) & 1u)) >> 16;
}
__device__ __forceinline__ float bflo(unsigned w) { return __uint_as_float(w << 16); }
__device__ __forceinline__ float bfhi(unsigned w) { return __uint_as_float(w & 0xFFFF0000u); }

// ---------------------------------------------------------------------------
// Row-level CSR offsets: histogram -> exclusive scan.
__global__ void hist_kernel(const int* __restrict__ rows, int* __restrict__ cnt,
                            int nnz) {
    int e = blockIdx.x * blockDim.x + threadIdx.x;
    if (e < nnz) atomicAdd(&cnt[rows[e]], 1);
}

// Generic per-block exclusive scan (in-place safe: src may == dst).
__global__ void scanA_kernel(const int* __restrict__ cnt, int* __restrict__ ofs,
                             int* __restrict__ bsum, int n) {
    int i = blockIdx.x * 256 + threadIdx.x;
    int v = (i < n) ? cnt[i] : 0;
    int lane = threadIdx.x & 63, w = threadIdx.x >> 6;
    int s = v;
    #pragma unroll
    for (int off = 1; off < 64; off <<= 1) {
        int t = __shfl_up(s, off, 64);
        if (lane >= off) s += t;
    }
    __shared__ int wsum[4];
    if (lane == 63) wsum[w] = s;
    __syncthreads();
    int add = 0;
    for (int k = 0; k < w; ++k) add += wsum[k];
    int incl = s + add;
    if (i < n) ofs[i] = incl - v;
    if (threadIdx.x == 255) bsum[blockIdx.x] = incl;
}

__global__ void scanB_kernel(int* __restrict__ bsum) {   // rows (SCAN_NB)
    int lane = threadIdx.x;                 // single wave
    int base = lane * SCANB_PER;
    int local[SCANB_PER];
    int s = 0;
    #pragma unroll
    for (int k = 0; k < SCANB_PER; ++k) {
        int idx = base + k;
        int t = (idx < SCAN_NB) ? bsum[idx] : 0;
        local[k] = s;
        s += t;
    }
    int incl = s;
    #pragma unroll
    for (int off = 1; off < 64; off <<= 1) {
        int t = __shfl_up(incl, off, 64);
        if (lane >= off) incl += t;
    }
    int excl = incl - s;
    #pragma unroll
    for (int k = 0; k < SCANB_PER; ++k) {
        int idx = base + k;
        if (idx < SCAN_NB) bsum[idx] = excl + local[k];
    }
}

// Generic single-wave scan of block sums (m <= 2560).
__global__ void scanB2_kernel(int* __restrict__ bsum, int m) {
    int lane = threadIdx.x;                 // 64 threads
    int per = (m + 63) >> 6;
    int local[40];                          // per <= 40
    int s = 0;
    for (int k = 0; k < per; ++k) {
        int idx = lane * per + k;
        int t = (idx < m) ? bsum[idx] : 0;
        local[k] = s;
        s += t;
    }
    int incl = s;
    #pragma unroll
    for (int off = 1; off < 64; off <<= 1) {
        int t = __shfl_up(incl, off, 64);
        if (lane >= off) incl += t;
    }
    int excl = incl - s;
    for (int k = 0; k < per; ++k) {
        int idx = lane * per + k;
        if (idx < m) bsum[idx] = excl + local[k];
    }
}

__global__ void scanC_kernel(int* __restrict__ ofs, const int* __restrict__ bsum,
                             int n, int nnz) {
    int i = blockIdx.x * 256 + threadIdx.x;
    if (i < n) ofs[i] += bsum[blockIdx.x];
    if (i == 0) ofs[n] = nnz;
}

// ---------------------------------------------------------------------------
// Zero-atomic radix scatter, phase 1a: per-(partition, block) counts via ballot.
__global__ void hist2_kernel(const int* __restrict__ rows,
                             int* __restrict__ bhist, int nnz, int nb2) {
    __shared__ int wcnt[4][NPART];
    int tid = threadIdx.x, lane = tid & 63, wv = tid >> 6;
    int e = blockIdx.x * 256 + tid;
    bool valid = e < nnz;
    int p = valid ? (rows[e] >> PSHIFT) : 0x7F;
    int cnt0 = 0, cnt1 = 0;
    for (int pp = 0; pp < NPART; ++pp) {
        unsigned long long mask = __ballot(p == pp);
        int c = (int)__popcll(mask);
        if (lane == (pp & 63)) { if (pp < 64) cnt0 = c; else cnt1 = c; }
    }
    wcnt[wv][lane] = cnt0;
    if (lane < NPART - 64) wcnt[wv][64 + lane] = cnt1;
    __syncthreads();
    if (tid < NPART)
        bhist[(size_t)tid * nb2 + blockIdx.x] =
            wcnt[0][tid] + wcnt[1][tid] + wcnt[2][tid] + wcnt[3][tid];
}

// Phase 1b: deterministic scatter using scanned bases. NO atomics.
__global__ void scatter2_kernel(const int* __restrict__ rows,
                                const int* __restrict__ cols,
                                const float* __restrict__ vals,
                                const int* __restrict__ sbase,
                                uint2* __restrict__ tmp_cv,
                                int* __restrict__ tmp_row, int nnz, int nb2) {
    __shared__ int wcnt[4][NPART];
    __shared__ int wbase[4][NPART];
    int tid = threadIdx.x, lane = tid & 63, wv = tid >> 6;
    int e = blockIdx.x * 256 + tid;
    bool valid = e < nnz;
    int r = valid ? rows[e] : 0;
    int p = valid ? (r >> PSHIFT) : 0x7F;
    unsigned long long ltmask = (1ull << lane) - 1ull;
    int myofs = 0, cnt0 = 0, cnt1 = 0;
    for (int pp = 0; pp < NPART; ++pp) {
        unsigned long long mask = __ballot(p == pp);
        if (p == pp) myofs = (int)__popcll(mask & ltmask);
        int c = (int)__popcll(mask);
        if (lane == (pp & 63)) { if (pp < 64) cnt0 = c; else cnt1 = c; }
    }
    wcnt[wv][lane] = cnt0;
    if (lane < NPART - 64) wcnt[wv][64 + lane] = cnt1;
    __syncthreads();
    if (tid < NPART) {
        int c0 = wcnt[0][tid], c1 = wcnt[1][tid], c2 = wcnt[2][tid];
        int g = sbase[(size_t)tid * nb2 + blockIdx.x];
        wbase[0][tid] = g;
        wbase[1][tid] = g + c0;
        wbase[2][tid] = g + c0 + c1;
        wbase[3][tid] = g + c0 + c1 + c2;
    }
    __syncthreads();
    if (valid) {
        int pos = wbase[wv][p] + myofs;
        tmp_cv[pos]  = make_uint2((unsigned)cols[e], __float_as_uint(vals[e]));
        tmp_row[pos] = r;
    }
}

// Phase 2: DETERMINISTIC per-partition sort. One block per partition; LDS row
// cursors. Per 1024-edge chunk: in-wave rank via 64-iter shfl loop; waves take
// barrier-serialized turns in which only the first-matching-lane "leader" does
// one atomicAdd(&cur[row], cnt). One add per (row,wave), distinct addresses per
// turn, turns ordered => every edge position is a pure function of the input.
__global__ __launch_bounds__(1024) void local_sort(
        const uint2* __restrict__ tmp_cv,
        const int* __restrict__ tmp_row,
        const int* __restrict__ pofs,      // scanned bhist: start at p*nb2
        const int* __restrict__ row_ofs,
        uint2* __restrict__ edge_cv, int nnz, int nb2) {
    __shared__ int cur[1 << PSHIFT];
    int p = blockIdx.x;
    int rbase = p << PSHIFT;
    int tid = threadIdx.x, lane = tid & 63, wv = tid >> 6;   // 16 waves
    for (int lr = tid; lr < (1 << PSHIFT); lr += 1024) {
        int r = rbase + lr;
        cur[lr] = (r < NQ) ? row_ofs[r] : 0;
    }
    __syncthreads();
    int beg = pofs[(size_t)p * nb2];
    int end = (p + 1 < NPART) ? pofs[(size_t)(p + 1) * nb2] : nnz;
    for (int chunk = beg; chunk < end; chunk += 1024) {
        int e = chunk + tid;
        bool valid = (e < end);
        int lr = valid ? (tmp_row[e] - rbase) : -1;
        uint2 cv = valid ? tmp_cv[e] : make_uint2(0u, 0u);
        // in-wave rank among same-row lanes; leader = first matching lane
        int rank = 0, cnt = 0, first = -1;
        for (int jj = 0; jj < 64; ++jj) {
            int rj = __shfl(lr, jj, 64);
            bool eq = (lr >= 0) && (rj == lr);
            if (eq) {
                ++cnt;
                if (jj < lane) ++rank;
                if (first < 0) first = jj;
            }
        }
        int base = 0;
        #pragma unroll
        for (int w2 = 0; w2 < 16; ++w2) {
            if (w2 == wv && lane == first)       // leader of its row, this wave
                base = atomicAdd(&cur[lr], cnt);
            __syncthreads();                     // uniform barrier, orders turns
        }
        base = __shfl(base, (first < 0) ? 0 : first, 64);
        if (valid) edge_cv[base + rank] = cv;
        __syncthreads();
    }
}

// all_emb -> bf16 table [N][64] (stored as uint[N][32], 2 dims per uint).
__global__ void conv_emb_kernel(const float* __restrict__ user_emb,
                                const float* __restrict__ item_emb,
                                unsigned int* __restrict__ embh) {
    size_t i = (size_t)blockIdx.x * blockDim.x + threadIdx.x;
    if (i >= (size_t)NQ * 32) return;
    size_t node = i >> 5; int j = (int)(i & 31);
    const float* src = (node < NUQ) ? (user_emb + node * DQ)
                                    : (item_emb + (node - NUQ) * DQ);
    embh[i] = f2bf(src[2 * j]) | (f2bf(src[2 * j + 1]) << 16);
}

// fc_w -> bf16 MFMA B-fragments, hi block [0,FRAGU) and lo residual block.
__global__ void fc_frag_kernel(const float* __restrict__ fc_w,
                               unsigned int* __restrict__ fcfrag) {
    int i = blockIdx.x * blockDim.x + threadIdx.x;
    if (i >= FRAGU) return;
    int k = i & 3;
    int l = (i >> 2) & 63;
    int f = i >> 8;
    int t = f >> 1, q = f & 1;
    int col = t * 16 + (l & 15);
    int krow = q * 32 + ((l >> 4) << 3) + 2 * k;
    float w0 = fc_w[krow * DQ + col];
    float w1 = fc_w[(krow + 1) * DQ + col];
    unsigned h0 = f2bf(w0), h1 = f2bf(w1);
    float r0 = w0 - __uint_as_float(h0 << 16);
    float r1 = w1 - __uint_as_float(h1 << 16);
    fcfrag[i]         = h0 | (h1 << 16);
    fcfrag[FRAGU + i] = f2bf(r0) | (f2bf(r1) << 16);
}

// Mark nodes whose layer-1 planes are ever read.
__global__ void mark_needed(const int* __restrict__ users,
                            const int* __restrict__ items,
                            const int* __restrict__ ofs,
                            const uint2* __restrict__ edge_cv,
                            unsigned char* __restrict__ needed, int B) {
    int wid  = (int)(((size_t)blockIdx.x * blockDim.x + threadIdx.x) >> 6);
    int lane = threadIdx.x & 63;
    if (wid >= 2 * B) return;
    int r = (wid < B) ? users[wid] : (NUQ + items[wid - B]);
    if (lane == 0) needed[r] = 1;
    int beg = ofs[r], end = ofs[r + 1];
    for (int i = beg + lane; i < end; i += 64) needed[(int)edge_cv[i].x] = 1;
}

// ---------------------------------------------------------------------------
// SpMM-only side pass. Half-split lanes, pair-loop unrolled x4.
__global__ void spmm_side_kernel(const unsigned int* __restrict__ embh,
                                 const int* __restrict__ ofs,
                                 const uint2* __restrict__ edge_cv,
                                 unsigned int* __restrict__ sideh,
                                 float* __restrict__ side32,
                                 unsigned char* __restrict__ mask8) {
    int wid  = (int)(((size_t)blockIdx.x * blockDim.x + threadIdx.x) >> 6);
    int lane = threadIdx.x & 63;
    if (wid >= NQ) return;
    int r = wid;
    int j = lane & 31, h = lane >> 5;
    int beg = ofs[r], end = ofs[r + 1];
    float acc0 = 0.f, acc1 = 0.f;     // dims (2j, 2j+1), this half's edges
    for (int base = beg; base < end; base += 64) {
        int n = end - base; if (n > 64) n = 64;
        int n1 = n - 1;
        uint2 cv = edge_cv[base + (lane < n ? lane : n1)];
        int   cc = (int)cv.x;
        float vv = __uint_as_float(cv.y);
        int npair = (n + 1) >> 1;
        for (int p = 0; p < npair; p += 4) {
            int i0 = 2 * p + h, i1 = i0 + 2, i2 = i0 + 4, i3 = i0 + 6;
            int k0 = (i0 <= n1) ? i0 : n1, k1 = (i1 <= n1) ? i1 : n1;
            int k2 = (i2 <= n1) ? i2 : n1, k3 = (i3 <= n1) ? i3 : n1;
            int c0 = __shfl(cc, k0, 64), c1 = __shfl(cc, k1, 64);
            int c2 = __shfl(cc, k2, 64), c3 = __shfl(cc, k3, 64);
            float v0 = __shfl(vv, k0, 64), v1 = __shfl(vv, k1, 64);
            float v2 = __shfl(vv, k2, 64), v3 = __shfl(vv, k3, 64);
            if (i0 > n1) v0 = 0.f;  if (i1 > n1) v1 = 0.f;
            if (i2 > n1) v2 = 0.f;  if (i3 > n1) v3 = 0.f;
            unsigned w0 = embh[((size_t)c0 << 5) + j];
            unsigned w1 = embh[((size_t)c1 << 5) + j];
            unsigned w2 = embh[((size_t)c2 << 5) + j];
            unsigned w3 = embh[((size_t)c3 << 5) + j];
            acc0 += v0 * bflo(w0);  acc1 += v0 * bfhi(w0);
            acc0 += v1 * bflo(w1);  acc1 += v1 * bfhi(w1);
            acc0 += v2 * bflo(w2);  acc1 += v2 * bfhi(w2);
            acc0 += v3 * bflo(w3);  acc1 += v3 * bfhi(w3);
        }
    }
    acc0 += __shfl_xor(acc0, 32, 64);
    acc1 += __shfl_xor(acc1, 32, 64);
    if (lane < 32) {
        sideh[((size_t)r << 5) + j] = f2bf(acc0) | (f2bf(acc1) << 16);
        ((float2*)(side32 + ((size_t)r << 6)))[j] = make_float2(acc0, acc1);
    }
    if (r >= NUQ && lane == 0) mask8[r] = 0xFu;   // items: all groups
}

// ---------------------------------------------------------------------------
// Scores via bf16x3 error-compensated MFMA: x@W ~= xh@Wh + xl@Wh + xh@Wl.
__global__ __launch_bounds__(256) void scores_mfma_kernel(
        const float* __restrict__ user_emb,
        const float* __restrict__ side32,
        const unsigned int* __restrict__ fcfrag,
        const float* __restrict__ fc_b,
        const float* __restrict__ fcg_w,
        const float* __restrict__ fcg_b,
        unsigned char* __restrict__ mask8,
        unsigned char* __restrict__ risky) {
    int lane = threadIdx.x & 63;
    int wave = threadIdx.x >> 6;
    int rowbase = blockIdx.x * 64 + wave * 16;
    if (rowbase >= NUQ) return;
    int l15 = lane & 15, l4 = lane >> 4;

    int arow = rowbase + l15; if (arow >= NUQ) arow = NUQ - 1;
    union { unsigned u[4]; bf16x8 v; } ah[2], al[2];
    #pragma unroll
    for (int q = 0; q < 2; ++q) {
        int k0 = q * 32 + (l4 << 3);
        const float* ue = user_emb + (size_t)arow * DQ + k0;
        const float* sp = side32   + (size_t)arow * DQ + k0;
        #pragma unroll
        for (int kk = 0; kk < 4; ++kk) {
            float x0 = ue[2 * kk]     + sp[2 * kk];
            float x1 = ue[2 * kk + 1] + sp[2 * kk + 1];
            unsigned h0 = f2bf(x0), h1 = f2bf(x1);
            ah[q].u[kk] = h0 | (h1 << 16);
            float r0 = x0 - __uint_as_float(h0 << 16);
            float r1 = x1 - __uint_as_float(h1 << 16);
            al[q].u[kk] = f2bf(r0) | (f2bf(r1) << 16);
        }
    }
    union { uint4v u; bf16x8 v; } bh[8], bl[8];
    const uint4v* bph = (const uint4v*)fcfrag;
    const uint4v* bpl = (const uint4v*)(fcfrag + FRAGU);
    #pragma unroll
    for (int f = 0; f < 8; ++f) { bh[f].u = bph[f * 64 + lane]; bl[f].u = bpl[f * 64 + lane]; }

    float y[4][4];
    #pragma unroll
    for (int t = 0; t < 4; ++t) {
        f32x4 acc = {0.f, 0.f, 0.f, 0.f};
        acc = __builtin_amdgcn_mfma_f32_16x16x32_bf16(ah[0].v, bh[t * 2 + 0].v, acc, 0, 0, 0);
        acc = __builtin_amdgcn_mfma_f32_16x16x32_bf16(ah[1].v, bh[t * 2 + 1].v, acc, 0, 0, 0);
        acc = __builtin_amdgcn_mfma_f32_16x16x32_bf16(al[0].v, bh[t * 2 + 0].v, acc, 0, 0, 0);
        acc = __builtin_amdgcn_mfma_f32_16x16x32_bf16(al[1].v, bh[t * 2 + 1].v, acc, 0, 0, 0);
        acc = __builtin_amdgcn_mfma_f32_16x16x32_bf16(ah[0].v, bl[t * 2 + 0].v, acc, 0, 0, 0);
        acc = __builtin_amdgcn_mfma_f32_16x16x32_bf16(ah[1].v, bl[t * 2 + 1].v, acc, 0, 0, 0);
        float fb = fc_b[t * 16 + l15];
        #pragma unroll
        for (int reg = 0; reg < 4; ++reg) {
            float v = acc[reg] + fb;
            y[t][reg] = (v > 0.f) ? v : 0.01f * v;   // leaky_relu
        }
    }
    float sg[GQ][4];
    #pragma unroll
    for (int g = 0; g < GQ; ++g) {
        float w0 = fcg_w[(0 * 16 + l15) * GQ + g];
        float w1 = fcg_w[(1 * 16 + l15) * GQ + g];
        float w2 = fcg_w[(2 * 16 + l15) * GQ + g];
        float w3 = fcg_w[(3 * 16 + l15) * GQ + g];
        #pragma unroll
        for (int reg = 0; reg < 4; ++reg) {
            float v = y[0][reg] * w0 + y[1][reg] * w1 + y[2][reg] * w2 + y[3][reg] * w3;
            v += __shfl_xor(v, 1, 64);
            v += __shfl_xor(v, 2, 64);
            v += __shfl_xor(v, 4, 64);
            v += __shfl_xor(v, 8, 64);
            sg[g][reg] = v + fcg_b[g];
        }
    }
    #pragma unroll
    for (int reg = 0; reg < 4; ++reg) {
        if (l15 == reg) {
            int row = rowbase + l4 * 4 + reg;
            if (row < NUQ) {
                float s0 = sg[0][reg], s1 = sg[1][reg], s2 = sg[2][reg], s3 = sg[3][reg];
                float m = fmaxf(fmaxf(s0, s1), fmaxf(s2, s3));
                int cnt = 0, arg = 0;
                if (m - s0 < EPSM) { ++cnt; arg = 0; }
                if (m - s1 < EPSM) { ++cnt; arg = 1; }
                if (m - s2 < EPSM) { ++cnt; arg = 2; }
                if (m - s3 < EPSM) { ++cnt; arg = 3; }
                if (cnt > 1) risky[row] = 1;
                else         mask8[row] = (unsigned char)(1u << arg);
            }
        }
    }
}

// f64 fixup for near-tie rows, from ORIGINAL f32 inputs (decision-exact).
__global__ void fix_risky_kernel(const float* __restrict__ user_emb,
                                 const float* __restrict__ item_emb,
                                 const float* __restrict__ fc_w,
                                 const float* __restrict__ fc_b,
                                 const float* __restrict__ fcg_w,
                                 const float* __restrict__ fcg_b,
                                 const int* __restrict__ ofs,
                                 const uint2* __restrict__ edge_cv,
                                 const unsigned char* __restrict__ risky,
                                 unsigned char* __restrict__ mask8) {
    int wid  = (int)(((size_t)blockIdx.x * blockDim.x + threadIdx.x) >> 6);
    int lane = threadIdx.x & 63;
    if (wid >= NUQ) return;
    int r = wid;
    if (!risky[r]) return;
    const float* ib = item_emb - (size_t)NUQ * DQ;
    int beg = ofs[r], end = ofs[r + 1];
    double a = 0.0;
    for (int i = beg; i < end; ++i) {
        uint2 cv = edge_cv[i];
        int c = (int)cv.x;
        const float* p = ((c < NUQ) ? user_emb : ib) + (size_t)c * DQ;
        a += (double)__uint_as_float(cv.y) * (double)p[lane];
    }
    double x = (double)user_emb[(size_t)r * DQ + lane] + a;
    double t = (double)fc_b[lane];
    for (int k = 0; k < DQ; ++k)
        t += __shfl(x, k, 64) * (double)fc_w[k * DQ + lane];
    t = (t > 0.0) ? t : 0.01 * t;
    double sg[GQ];
    #pragma unroll
    for (int g = 0; g < GQ; ++g) {
        double v2 = t * (double)fcg_w[lane * GQ + g];
        #pragma unroll
        for (int off = 32; off > 0; off >>= 1) v2 += __shfl_xor(v2, off, 64);
        sg[g] = v2 + (double)fcg_b[g];
    }
    double m = fmax(fmax(sg[0], sg[1]), fmax(sg[2], sg[3]));
    unsigned bits = 0;
    #pragma unroll
    for (int g = 0; g < GQ; ++g) if (sg[g] == m) bits |= (1u << g);
    if (lane == 0) mask8[r] = (unsigned char)bits;
}

// ---------------------------------------------------------------------------
// Layer 1 for needed rows, gathering bf16 side. emb4 layout [N][4][64] f32.
__global__ void layer1_kernel(const int* __restrict__ ofs,
                              const uint2* __restrict__ edge_cv,
                              const unsigned char* __restrict__ mask8,
                              const unsigned char* __restrict__ needed,
                              const unsigned int* __restrict__ sideh,
                              float* __restrict__ emb4) {
    int wid  = (int)(((size_t)blockIdx.x * blockDim.x + threadIdx.x) >> 6);
    int lane = threadIdx.x & 63;
    if (wid >= NQ) return;
    int r = wid;
    if (!needed[r]) return;
    unsigned mr = mask8[r];
    int j = lane & 31, h = lane >> 5;
    int beg = ofs[r], end = ofs[r + 1];
    bool single = (mr & (mr - 1u)) == 0u;

    if (single) {
        float acc0 = 0.f, acc1 = 0.f;
        for (int base = beg; base < end; base += 64) {
            int n = end - base; if (n > 64) n = 64;
            int n1 = n - 1;
            uint2 cv = edge_cv[base + (lane < n ? lane : n1)];
            int   cc = (int)cv.x;
            float vv = __uint_as_float(cv.y);
            int pack = cc | ((int)(mr & (unsigned)mask8[cc]) << 20);
            int npair = (n + 1) >> 1;
            for (int p = 0; p < npair; p += 4) {
                int i0 = 2 * p + h, i1 = i0 + 2, i2 = i0 + 4, i3 = i0 + 6;
                int k0 = (i0 <= n1) ? i0 : n1, k1 = (i1 <= n1) ? i1 : n1;
                int k2 = (i2 <= n1) ? i2 : n1, k3 = (i3 <= n1) ? i3 : n1;
                int w0 = __shfl(pack, k0, 64), w1 = __shfl(pack, k1, 64);
                int w2 = __shfl(pack, k2, 64), w3 = __shfl(pack, k3, 64);
                float v0 = __shfl(vv, k0, 64), v1 = __shfl(vv, k1, 64);
                float v2 = __shfl(vv, k2, 64), v3 = __shfl(vv, k3, 64);
                if (i0 > n1 || !((unsigned)w0 >> 20)) v0 = 0.f;
                if (i1 > n1 || !((unsigned)w1 >> 20)) v1 = 0.f;
                if (i2 > n1 || !((unsigned)w2 >> 20)) v2 = 0.f;
                if (i3 > n1 || !((unsigned)w3 >> 20)) v3 = 0.f;
                unsigned e0 = sideh[((size_t)(w0 & 0xFFFFF) << 5) + j];
                unsigned e1 = sideh[((size_t)(w1 & 0xFFFFF) << 5) + j];
                unsigned e2 = sideh[((size_t)(w2 & 0xFFFFF) << 5) + j];
                unsigned e3 = sideh[((size_t)(w3 & 0xFFFFF) << 5) + j];
                acc0 += v0 * bflo(e0);  acc1 += v0 * bfhi(e0);
                acc0 += v1 * bflo(e1);  acc1 += v1 * bfhi(e1);
                acc0 += v2 * bflo(e2);  acc1 += v2 * bfhi(e2);
                acc0 += v3 * bflo(e3);  acc1 += v3 * bfhi(e3);
            }
        }
        acc0 += __shfl_xor(acc0, 32, 64);
        acc1 += __shfl_xor(acc1, 32, 64);
        int p = __ffs((int)mr) - 1;
        if (lane < 32) {
            float2* dst = (float2*)(emb4 + (((size_t)r * GQ + p) << 6));
            dst[j] = make_float2(acc0, acc1);
        }
    } else {
        float b0 = 0.f, b1 = 0.f, b2 = 0.f, b3 = 0.f;   // dim 2j, planes 0-3
        float d0 = 0.f, d1 = 0.f, d2 = 0.f, d3 = 0.f;   // dim 2j+1
        for (int base = beg; base < end; base += 64) {
            int n = end - base; if (n > 64) n = 64;
            int n1 = n - 1;
            uint2 cv = edge_cv[base + (lane < n ? lane : n1)];
            int   cc = (int)cv.x;
            float vv = __uint_as_float(cv.y);
            int pack = cc | ((int)(mr & (unsigned)mask8[cc]) << 20);
            int npair = (n + 1) >> 1;
            for (int p = 0; p < npair; p += 2) {
                int ia = 2 * p + h, ibx = ia + 2;
                int ka = (ia <= n1) ? ia : n1, kb = (ibx <= n1) ? ibx : n1;
                int wa = __shfl(pack, ka, 64), wb = __shfl(pack, kb, 64);
                float va = __shfl(vv, ka, 64), vb = __shfl(vv, kb, 64);
                if (ia > n1)  va = 0.f;
                if (ibx > n1) vb = 0.f;
                unsigned ea = sideh[((size_t)(wa & 0xFFFFF) << 5) + j];
                unsigned eb = sideh[((size_t)(wb & 0xFFFFF) << 5) + j];
                unsigned ma = (unsigned)wa >> 20, mb = (unsigned)wb >> 20;
                float fa0 = va * bflo(ea), fa1 = va * bfhi(ea);
                float fb0 = vb * bflo(eb), fb1 = vb * bfhi(eb);
                b0 += (ma & 1u) ? fa0 : 0.f;  d0 += (ma & 1u) ? fa1 : 0.f;
                b1 += (ma & 2u) ? fa0 : 0.f;  d1 += (ma & 2u) ? fa1 : 0.f;
                b2 += (ma & 4u) ? fa0 : 0.f;  d2 += (ma & 4u) ? fa1 : 0.f;
                b3 += (ma & 8u) ? fa0 : 0.f;  d3 += (ma & 8u) ? fa1 : 0.f;
                b0 += (mb & 1u) ? fb0 : 0.f;  d0 += (mb & 1u) ? fb1 : 0.f;
                b1 += (mb & 2u) ? fb0 : 0.f;  d1 += (mb & 2u) ? fb1 : 0.f;
                b2 += (mb & 4u) ? fb0 : 0.f;  d2 += (mb & 4u) ? fb1 : 0.f;
                b3 += (mb & 8u) ? fb0 : 0.f;  d3 += (mb & 8u) ? fb1 : 0.f;
            }
        }
        b0 += __shfl_xor(b0, 32, 64);  d0 += __shfl_xor(d0, 32, 64);
        b1 += __shfl_xor(b1, 32, 64);  d1 += __shfl_xor(d1, 32, 64);
        b2 += __shfl_xor(b2, 32, 64);  d2 += __shfl_xor(d2, 32, 64);
        b3 += __shfl_xor(b3, 32, 64);  d3 += __shfl_xor(d3, 32, 64);
        if (lane < 32) {
            float2* dst = (float2*)(emb4 + (((size_t)r * GQ) << 6));
            dst[j]      = make_float2(b0, d0);
            dst[j + 32] = make_float2(b1, d1);
            dst[j + 64] = make_float2(b2, d2);
            dst[j + 96] = make_float2(b3, d3);
        }
    }
}

// ---------------------------------------------------------------------------
// Fused layer2 + gamma, sampled rows only.
__device__ __forceinline__ float l2_row(int r, int lane, unsigned mr,
                                        const int* __restrict__ ofs,
                                        const uint2* __restrict__ edge_cv,
                                        const unsigned char* __restrict__ mask8,
                                        const float* __restrict__ emb4) {
    float sum = 0.f;
    int beg = ofs[r], end = ofs[r + 1];
    for (int base = beg; base < end; base += 64) {
        int n = end - base; if (n > 64) n = 64;
        int n1 = n - 1;
        uint2 cv = edge_cv[base + (lane < n ? lane : n1)];
        int   cc = (int)cv.x;
        float vv = __uint_as_float(cv.y);
        int pack = cc | ((int)(mr & (unsigned)mask8[cc]) << 20);
        for (int e = 0; e < n; ++e) {
            int w = __shfl(pack, e, 64);
            unsigned mb = ((unsigned)w >> 20) & 0xFu;
            if (!mb) continue;
            float v = __shfl(vv, e, 64);
            size_t co = (size_t)(w & 0xFFFFF) * (GQ * DQ) + lane;
            if (mb == 0xFu) {
                sum += v * (emb4[co] + emb4[co + DQ] + emb4[co + 2 * DQ] + emb4[co + 3 * DQ]);
            } else if ((mb & (mb - 1u)) == 0u) {
                sum += v * emb4[co + ((__ffs((int)mb) - 1) << 6)];
            } else {
                #pragma unroll
                for (int g = 0; g < GQ; ++g)
                    if ((mb >> g) & 1u) sum += v * emb4[co + (g << 6)];
            }
        }
    }
    return sum;
}

__global__ void gamma_kernel(const int* __restrict__ ofs,
                             const uint2* __restrict__ edge_cv,
                             const unsigned char* __restrict__ mask8,
                             const float* __restrict__ side32,
                             const float* __restrict__ emb4,
                             const int* __restrict__ users,
                             const int* __restrict__ items,
                             float* __restrict__ out, int B) {
    int wid  = (int)(((size_t)blockIdx.x * blockDim.x + threadIdx.x) >> 6);
    int lane = threadIdx.x & 63;
    if (wid >= B) return;
    int u  = users[wid];
    int it = NUQ + items[wid];
    unsigned mu = mask8[u];
    size_t uo = (size_t)u * GQ * DQ + lane;
    size_t io = (size_t)it * GQ * DQ + lane;
    float baseu = 0.f;
    #pragma unroll
    for (int g = 0; g < GQ; ++g)
        if ((mu >> g) & 1u) baseu += emb4[uo + (g << 6)];
    float basei = emb4[io] + emb4[io + DQ] + emb4[io + 2 * DQ] + emb4[io + 3 * DQ];
    float su = side32[(size_t)u * DQ + lane];
    float si = side32[(size_t)it * DQ + lane];
    float fu = 4.f * su + baseu + l2_row(u, lane, mu, ofs, edge_cv, mask8, emb4);
    float fi = 4.f * si + basei + l2_row(it, lane, 0xFu, ofs, edge_cv, mask8, emb4);
    float p = fu * fi;
    #pragma unroll
    for (int off = 32; off > 0; off >>= 1) p += __shfl_xor(p, off, 64);
    if (lane == 0) out[wid] = 0.04f * p;   // 0.2^2
}

// ---------------------------------------------------------------------------
extern "C" void kernel_launch(void* const* d_in, const int* in_sizes, int n_in,
                              void* d_out, int out_size, void* d_ws, size_t ws_size,
                              hipStream_t stream) {
    const float* user_emb = (const float*)d_in[0];
    const float* item_emb = (const float*)d_in[1];
    const float* fc_w     = (const float*)d_in[2];
    const float* fc_b     = (const float*)d_in[3];
    const float* fcg_w    = (const float*)d_in[4];
    const float* fcg_b    = (const float*)d_in[5];
    const float* vals     = (const float*)d_in[6];
    const int*   rows     = (const int*)d_in[7];
    const int*   cols     = (const int*)d_in[8];
    const int*   users    = (const int*)d_in[9];
    const int*   items    = (const int*)d_in[10];
    const int nnz = in_sizes[6];
    const int B   = in_sizes[9];
    float* out = (float*)d_out;

    const size_t ND = (size_t)NQ * DQ;

    char* ws = (char*)d_ws;
    size_t off = 0;
    float* emb4 = (float*)(ws + off); off += 4 * ND * sizeof(float);           // 153.6 MB
    unsigned int* embh  = (unsigned int*)(ws + off); off += ND * 2;            //  19.2 MB
    unsigned int* sideh = (unsigned int*)(ws + off); off += ND * 2;            //  19.2 MB
    float* side32 = (float*)(ws + off); off += ND * sizeof(float);             //  38.4 MB
    uint2* edge_cv = (uint2*)(ws + off); off += (size_t)nnz * 8;               //  16.0 MB
    int* row_ofs  = (int*)(ws + off); off += ((size_t)(NQ + 1) * 4 + 255) / 256 * 256;
    int* bsum     = (int*)(ws + off); off += ((size_t)SCAN_NB * 4 + 255) / 256 * 256;
    unsigned int* fcfrag = (unsigned int*)(ws + off); off += 2 * FRAGU * 4;    //  16 KB
    // contiguous zero-init block: row_cnt, needed/risky bytes
    char* zblock = ws + off;
    int* row_cnt  = (int*)(ws + off); off += (size_t)NQ * 4;
    unsigned char* needed = (unsigned char*)(ws + off); off += ((size_t)NQ + 255) / 256 * 256;
    unsigned char* risky  = (unsigned char*)(ws + off); off += ((size_t)NUQ + 255) / 256 * 256;
    size_t zbytes = (size_t)(ws + off - zblock);
    unsigned char* mask8  = (unsigned char*)(ws + off); off += ((size_t)NQ + 255) / 256 * 256;

    // Radix-build temporaries ALIAS emb4 (emb4 not live during CSR build):
    const int NB2 = (nnz + 255) / 256;
    const int M   = NPART * NB2;
    const int M2  = (M + 255) / 256;
    uint2* tmp_cv  = (uint2*)emb4;                                      // nnz*8
    int*   tmp_row = (int*)((char*)emb4 + (size_t)nnz * 8);             // nnz*4
    int*   bhist   = (int*)((char*)emb4 + ((size_t)nnz * 12 + 255) / 256 * 256); // (M+1)*4
    int*   bsum2   = bhist + ((M + 64) / 64 * 64);                      // M2*4

    // --- CSR build: row offsets + zero-atomic radix scatter ---
    hipMemsetAsync(zblock, 0, zbytes, stream);
    hist_kernel<<<(nnz + 255) / 256, 256, 0, stream>>>(rows, row_cnt, nnz);
    scanA_kernel<<<SCAN_NB, 256, 0, stream>>>(row_cnt, row_ofs, bsum, NQ);
    scanB_kernel<<<1, 64, 0, stream>>>(bsum);
    scanC_kernel<<<SCAN_NB, 256, 0, stream>>>(row_ofs, bsum, NQ, nnz);

    hist2_kernel<<<NB2, 256, 0, stream>>>(rows, bhist, nnz, NB2);
    scanA_kernel<<<M2, 256, 0, stream>>>(bhist, bhist, bsum2, M);
    scanB2_kernel<<<1, 64, 0, stream>>>(bsum2, M2);
    scanC_kernel<<<M2, 256, 0, stream>>>(bhist, bsum2, M, nnz);
    scatter2_kernel<<<NB2, 256, 0, stream>>>(rows, cols, vals, bhist,
                                             tmp_cv, tmp_row, nnz, NB2);
    local_sort<<<NPART, 1024, 0, stream>>>(tmp_cv, tmp_row, bhist, row_ofs,
                                           edge_cv, nnz, NB2);

    conv_emb_kernel<<<(int)((ND / 2 + 255) / 256), 256, 0, stream>>>(
        user_emb, item_emb, embh);
    fc_frag_kernel<<<8, 256, 0, stream>>>(fc_w, fcfrag);
    mark_needed<<<(2 * B * 64 + 255) / 256, 256, 0, stream>>>(
        users, items, row_ofs, edge_cv, needed, B);

    // --- side SpMM (all rows) ---
    const int row_blocks = (NQ * 64 + 255) / 256;   // 4 waves/block
    spmm_side_kernel<<<row_blocks, 256, 0, stream>>>(embh, row_ofs, edge_cv,
                                                     sideh, side32, mask8);

    // --- user scores via bf16x3 MFMA -> masks (+risky) ---
    scores_mfma_kernel<<<(NUQ + 63) / 64, 256, 0, stream>>>(
        user_emb, side32, fcfrag, fc_b, fcg_w, fcg_b, mask8, risky);
    fix_risky_kernel<<<(NUQ * 64 + 255) / 256, 256, 0, stream>>>(
        user_emb, item_emb, fc_w, fc_b, fcg_w, fcg_b,
        row_ofs, edge_cv, risky, mask8);

    // --- layer 1 (needed rows only) ---
    layer1_kernel<<<row_blocks, 256, 0, stream>>>(row_ofs, edge_cv, mask8,
                                                  needed, sideh, emb4);

    // --- fused layer2 + gamma (sampled rows only) ---
    gamma_kernel<<<((size_t)B * 64 + 255) / 256, 256, 0, stream>>>(
        row_ofs, edge_cv, mask8, side32, emb4, users, items, out, B);
}

// Round 15
// 463.736 us; speedup vs baseline: 1.1785x; 1.1785x over previous
//
#include <hip/hip_runtime.h>
#include <hip/hip_bf16.h>

// LightGCN_27384711480190 — r15: revert to r12 final_scatter (replay-stable,
// fast); spmm_side widened to 8 gathers in flight.
#define NUQ 100000   // users
#define NIQ 50000    // items
#define NQ  150000   // N = NU + NI
#define DQ  64       // embedding dim (== wavefront)
#define GQ  4        // groups
#define EPSM 1e-2f   // argmax margin; bf16x3 score err ~1e-3 tail

#define SCAN_NB  ((NQ + 255) / 256)
#define SCANB_PER ((SCAN_NB + 63) / 64)
#define PSHIFT 11
#define NPART ((NQ + (1 << PSHIFT) - 1) >> PSHIFT)   // 74 partitions of 2048 rows
#define FRAGU (8 * 64 * 4)                           // uints per fragment block

typedef __attribute__((ext_vector_type(8))) short bf16x8;
typedef __attribute__((ext_vector_type(4))) float f32x4;
typedef __attribute__((ext_vector_type(4))) unsigned int uint4v;

__device__ __forceinline__ unsigned f2bf(float f) {   // RNE f32 -> bf16 bits
    unsigned u = __float_as_uint(f);
    return (u + 0x7FFFu + ((u >> 16) & 1u)) >> 16;
}
__device__ __forceinline__ float bflo(unsigned w) { return __uint_as_float(w << 16); }
__device__ __forceinline__ float bfhi(unsigned w) { return __uint_as_float(w & 0xFFFF0000u); }

// ---------------------------------------------------------------------------
// Row-level CSR offsets: histogram -> exclusive scan.
__global__ void hist_kernel(const int* __restrict__ rows, int* __restrict__ cnt,
                            int nnz) {
    int e = blockIdx.x * blockDim.x + threadIdx.x;
    if (e < nnz) atomicAdd(&cnt[rows[e]], 1);
}

// Generic per-block exclusive scan (in-place safe: src may == dst).
__global__ void scanA_kernel(const int* __restrict__ cnt, int* __restrict__ ofs,
                             int* __restrict__ bsum, int n) {
    int i = blockIdx.x * 256 + threadIdx.x;
    int v = (i < n) ? cnt[i] : 0;
    int lane = threadIdx.x & 63, w = threadIdx.x >> 6;
    int s = v;
    #pragma unroll
    for (int off = 1; off < 64; off <<= 1) {
        int t = __shfl_up(s, off, 64);
        if (lane >= off) s += t;
    }
    __shared__ int wsum[4];
    if (lane == 63) wsum[w] = s;
    __syncthreads();
    int add = 0;
    for (int k = 0; k < w; ++k) add += wsum[k];
    int incl = s + add;
    if (i < n) ofs[i] = incl - v;
    if (threadIdx.x == 255) bsum[blockIdx.x] = incl;
}

__global__ void scanB_kernel(int* __restrict__ bsum) {   // rows (SCAN_NB)
    int lane = threadIdx.x;                 // single wave
    int base = lane * SCANB_PER;
    int local[SCANB_PER];
    int s = 0;
    #pragma unroll
    for (int k = 0; k < SCANB_PER; ++k) {
        int idx = base + k;
        int t = (idx < SCAN_NB) ? bsum[idx] : 0;
        local[k] = s;
        s += t;
    }
    int incl = s;
    #pragma unroll
    for (int off = 1; off < 64; off <<= 1) {
        int t = __shfl_up(incl, off, 64);
        if (lane >= off) incl += t;
    }
    int excl = incl - s;
    #pragma unroll
    for (int k = 0; k < SCANB_PER; ++k) {
        int idx = base + k;
        if (idx < SCAN_NB) bsum[idx] = excl + local[k];
    }
}

// Generic single-wave scan of block sums (m <= 2560).
__global__ void scanB2_kernel(int* __restrict__ bsum, int m) {
    int lane = threadIdx.x;                 // 64 threads
    int per = (m + 63) >> 6;
    int local[40];                          // per <= 40
    int s = 0;
    for (int k = 0; k < per; ++k) {
        int idx = lane * per + k;
        int t = (idx < m) ? bsum[idx] : 0;
        local[k] = s;
        s += t;
    }
    int incl = s;
    #pragma unroll
    for (int off = 1; off < 64; off <<= 1) {
        int t = __shfl_up(incl, off, 64);
        if (lane >= off) incl += t;
    }
    int excl = incl - s;
    for (int k = 0; k < per; ++k) {
        int idx = lane * per + k;
        if (idx < m) bsum[idx] = excl + local[k];
    }
}

__global__ void scanC_kernel(int* __restrict__ ofs, const int* __restrict__ bsum,
                             int n, int nnz) {
    int i = blockIdx.x * 256 + threadIdx.x;
    if (i < n) ofs[i] += bsum[blockIdx.x];
    if (i == 0) ofs[n] = nnz;
}

// ---------------------------------------------------------------------------
// Zero-atomic radix scatter, phase 1a: per-(partition, block) counts via ballot.
__global__ void hist2_kernel(const int* __restrict__ rows,
                             int* __restrict__ bhist, int nnz, int nb2) {
    __shared__ int wcnt[4][NPART];
    int tid = threadIdx.x, lane = tid & 63, wv = tid >> 6;
    int e = blockIdx.x * 256 + tid;
    bool valid = e < nnz;
    int p = valid ? (rows[e] >> PSHIFT) : 0x7F;
    int cnt0 = 0, cnt1 = 0;
    for (int pp = 0; pp < NPART; ++pp) {
        unsigned long long mask = __ballot(p == pp);
        int c = (int)__popcll(mask);
        if (lane == (pp & 63)) { if (pp < 64) cnt0 = c; else cnt1 = c; }
    }
    wcnt[wv][lane] = cnt0;
    if (lane < NPART - 64) wcnt[wv][64 + lane] = cnt1;
    __syncthreads();
    if (tid < NPART)
        bhist[(size_t)tid * nb2 + blockIdx.x] =
            wcnt[0][tid] + wcnt[1][tid] + wcnt[2][tid] + wcnt[3][tid];
}

// Phase 1b: deterministic scatter using scanned bases. NO atomics.
__global__ void scatter2_kernel(const int* __restrict__ rows,
                                const int* __restrict__ cols,
                                const float* __restrict__ vals,
                                const int* __restrict__ sbase,
                                uint2* __restrict__ tmp_cv,
                                int* __restrict__ tmp_row, int nnz, int nb2) {
    __shared__ int wcnt[4][NPART];
    __shared__ int wbase[4][NPART];
    int tid = threadIdx.x, lane = tid & 63, wv = tid >> 6;
    int e = blockIdx.x * 256 + tid;
    bool valid = e < nnz;
    int r = valid ? rows[e] : 0;
    int p = valid ? (r >> PSHIFT) : 0x7F;
    unsigned long long ltmask = (1ull << lane) - 1ull;
    int myofs = 0, cnt0 = 0, cnt1 = 0;
    for (int pp = 0; pp < NPART; ++pp) {
        unsigned long long mask = __ballot(p == pp);
        if (p == pp) myofs = (int)__popcll(mask & ltmask);
        int c = (int)__popcll(mask);
        if (lane == (pp & 63)) { if (pp < 64) cnt0 = c; else cnt1 = c; }
    }
    wcnt[wv][lane] = cnt0;
    if (lane < NPART - 64) wcnt[wv][64 + lane] = cnt1;
    __syncthreads();
    if (tid < NPART) {
        int c0 = wcnt[0][tid], c1 = wcnt[1][tid], c2 = wcnt[2][tid];
        int g = sbase[(size_t)tid * nb2 + blockIdx.x];
        wbase[0][tid] = g;
        wbase[1][tid] = g + c0;
        wbase[2][tid] = g + c0 + c1;
        wbase[3][tid] = g + c0 + c1 + c2;
    }
    __syncthreads();
    if (valid) {
        int pos = wbase[wv][p] + myofs;
        tmp_cv[pos]  = make_uint2((unsigned)cols[e], __float_as_uint(vals[e]));
        tmp_row[pos] = r;
    }
}

// Phase 2 (r12 form): read partition-grouped tmp coalesced; place at final CSR
// slot. Write window per block ~ one partition (L2-resident). Global fill
// atomics; replay-stable empirically (r10-r12, 3/3 tripwire passes).
__global__ void final_scatter(const uint2* __restrict__ tmp_cv,
                              const int* __restrict__ tmp_row,
                              const int* __restrict__ ofs,
                              int* __restrict__ fill,
                              uint2* __restrict__ edge_cv, int nnz) {
    int e = blockIdx.x * 256 + threadIdx.x;
    if (e >= nnz) return;
    int r = tmp_row[e];
    int pos = ofs[r] + atomicAdd(&fill[r], 1);
    edge_cv[pos] = tmp_cv[e];
}

// all_emb -> bf16 table [N][64] (stored as uint[N][32], 2 dims per uint).
__global__ void conv_emb_kernel(const float* __restrict__ user_emb,
                                const float* __restrict__ item_emb,
                                unsigned int* __restrict__ embh) {
    size_t i = (size_t)blockIdx.x * blockDim.x + threadIdx.x;
    if (i >= (size_t)NQ * 32) return;
    size_t node = i >> 5; int j = (int)(i & 31);
    const float* src = (node < NUQ) ? (user_emb + node * DQ)
                                    : (item_emb + (node - NUQ) * DQ);
    embh[i] = f2bf(src[2 * j]) | (f2bf(src[2 * j + 1]) << 16);
}

// fc_w -> bf16 MFMA B-fragments, hi block [0,FRAGU) and lo residual block.
__global__ void fc_frag_kernel(const float* __restrict__ fc_w,
                               unsigned int* __restrict__ fcfrag) {
    int i = blockIdx.x * blockDim.x + threadIdx.x;
    if (i >= FRAGU) return;
    int k = i & 3;
    int l = (i >> 2) & 63;
    int f = i >> 8;
    int t = f >> 1, q = f & 1;
    int col = t * 16 + (l & 15);
    int krow = q * 32 + ((l >> 4) << 3) + 2 * k;
    float w0 = fc_w[krow * DQ + col];
    float w1 = fc_w[(krow + 1) * DQ + col];
    unsigned h0 = f2bf(w0), h1 = f2bf(w1);
    float r0 = w0 - __uint_as_float(h0 << 16);
    float r1 = w1 - __uint_as_float(h1 << 16);
    fcfrag[i]         = h0 | (h1 << 16);
    fcfrag[FRAGU + i] = f2bf(r0) | (f2bf(r1) << 16);
}

// Mark nodes whose layer-1 planes are ever read.
__global__ void mark_needed(const int* __restrict__ users,
                            const int* __restrict__ items,
                            const int* __restrict__ ofs,
                            const uint2* __restrict__ edge_cv,
                            unsigned char* __restrict__ needed, int B) {
    int wid  = (int)(((size_t)blockIdx.x * blockDim.x + threadIdx.x) >> 6);
    int lane = threadIdx.x & 63;
    if (wid >= 2 * B) return;
    int r = (wid < B) ? users[wid] : (NUQ + items[wid - B]);
    if (lane == 0) needed[r] = 1;
    int beg = ofs[r], end = ofs[r + 1];
    for (int i = beg + lane; i < end; i += 64) needed[(int)edge_cv[i].x] = 1;
}

// ---------------------------------------------------------------------------
// SpMM-only side pass. Half-split lanes, pair-loop with 8 gathers in flight.
__global__ void spmm_side_kernel(const unsigned int* __restrict__ embh,
                                 const int* __restrict__ ofs,
                                 const uint2* __restrict__ edge_cv,
                                 unsigned int* __restrict__ sideh,
                                 float* __restrict__ side32,
                                 unsigned char* __restrict__ mask8) {
    int wid  = (int)(((size_t)blockIdx.x * blockDim.x + threadIdx.x) >> 6);
    int lane = threadIdx.x & 63;
    if (wid >= NQ) return;
    int r = wid;
    int j = lane & 31, h = lane >> 5;
    int beg = ofs[r], end = ofs[r + 1];
    float acc0 = 0.f, acc1 = 0.f;     // dims (2j, 2j+1), this half's edges
    for (int base = beg; base < end; base += 64) {
        int n = end - base; if (n > 64) n = 64;
        int n1 = n - 1;
        uint2 cv = edge_cv[base + (lane < n ? lane : n1)];
        int   cc = (int)cv.x;
        float vv = __uint_as_float(cv.y);
        int npair = (n + 1) >> 1;
        for (int p = 0; p < npair; p += 8) {
            int   ccc[8];
            float vvv[8];
            #pragma unroll
            for (int u = 0; u < 8; ++u) {
                int iu = 2 * (p + u) + h;
                int ku = (iu <= n1) ? iu : n1;
                ccc[u] = __shfl(cc, ku, 64);
                float vu = __shfl(vv, ku, 64);
                vvv[u] = (iu > n1) ? 0.f : vu;
            }
            unsigned ww[8];
            #pragma unroll
            for (int u = 0; u < 8; ++u)
                ww[u] = embh[((size_t)ccc[u] << 5) + j];
            #pragma unroll
            for (int u = 0; u < 8; ++u) {
                acc0 += vvv[u] * bflo(ww[u]);
                acc1 += vvv[u] * bfhi(ww[u]);
            }
        }
    }
    acc0 += __shfl_xor(acc0, 32, 64);
    acc1 += __shfl_xor(acc1, 32, 64);
    if (lane < 32) {
        sideh[((size_t)r << 5) + j] = f2bf(acc0) | (f2bf(acc1) << 16);
        ((float2*)(side32 + ((size_t)r << 6)))[j] = make_float2(acc0, acc1);
    }
    if (r >= NUQ && lane == 0) mask8[r] = 0xFu;   // items: all groups
}

// ---------------------------------------------------------------------------
// Scores via bf16x3 error-compensated MFMA: x@W ~= xh@Wh + xl@Wh + xh@Wl.
__global__ __launch_bounds__(256) void scores_mfma_kernel(
        const float* __restrict__ user_emb,
        const float* __restrict__ side32,
        const unsigned int* __restrict__ fcfrag,
        const float* __restrict__ fc_b,
        const float* __restrict__ fcg_w,
        const float* __restrict__ fcg_b,
        unsigned char* __restrict__ mask8,
        unsigned char* __restrict__ risky) {
    int lane = threadIdx.x & 63;
    int wave = threadIdx.x >> 6;
    int rowbase = blockIdx.x * 64 + wave * 16;
    if (rowbase >= NUQ) return;
    int l15 = lane & 15, l4 = lane >> 4;

    int arow = rowbase + l15; if (arow >= NUQ) arow = NUQ - 1;
    union { unsigned u[4]; bf16x8 v; } ah[2], al[2];
    #pragma unroll
    for (int q = 0; q < 2; ++q) {
        int k0 = q * 32 + (l4 << 3);
        const float* ue = user_emb + (size_t)arow * DQ + k0;
        const float* sp = side32   + (size_t)arow * DQ + k0;
        #pragma unroll
        for (int kk = 0; kk < 4; ++kk) {
            float x0 = ue[2 * kk]     + sp[2 * kk];
            float x1 = ue[2 * kk + 1] + sp[2 * kk + 1];
            unsigned h0 = f2bf(x0), h1 = f2bf(x1);
            ah[q].u[kk] = h0 | (h1 << 16);
            float r0 = x0 - __uint_as_float(h0 << 16);
            float r1 = x1 - __uint_as_float(h1 << 16);
            al[q].u[kk] = f2bf(r0) | (f2bf(r1) << 16);
        }
    }
    union { uint4v u; bf16x8 v; } bh[8], bl[8];
    const uint4v* bph = (const uint4v*)fcfrag;
    const uint4v* bpl = (const uint4v*)(fcfrag + FRAGU);
    #pragma unroll
    for (int f = 0; f < 8; ++f) { bh[f].u = bph[f * 64 + lane]; bl[f].u = bpl[f * 64 + lane]; }

    float y[4][4];
    #pragma unroll
    for (int t = 0; t < 4; ++t) {
        f32x4 acc = {0.f, 0.f, 0.f, 0.f};
        acc = __builtin_amdgcn_mfma_f32_16x16x32_bf16(ah[0].v, bh[t * 2 + 0].v, acc, 0, 0, 0);
        acc = __builtin_amdgcn_mfma_f32_16x16x32_bf16(ah[1].v, bh[t * 2 + 1].v, acc, 0, 0, 0);
        acc = __builtin_amdgcn_mfma_f32_16x16x32_bf16(al[0].v, bh[t * 2 + 0].v, acc, 0, 0, 0);
        acc = __builtin_amdgcn_mfma_f32_16x16x32_bf16(al[1].v, bh[t * 2 + 1].v, acc, 0, 0, 0);
        acc = __builtin_amdgcn_mfma_f32_16x16x32_bf16(ah[0].v, bl[t * 2 + 0].v, acc, 0, 0, 0);
        acc = __builtin_amdgcn_mfma_f32_16x16x32_bf16(ah[1].v, bl[t * 2 + 1].v, acc, 0, 0, 0);
        float fb = fc_b[t * 16 + l15];
        #pragma unroll
        for (int reg = 0; reg < 4; ++reg) {
            float v = acc[reg] + fb;
            y[t][reg] = (v > 0.f) ? v : 0.01f * v;   // leaky_relu
        }
    }
    float sg[GQ][4];
    #pragma unroll
    for (int g = 0; g < GQ; ++g) {
        float w0 = fcg_w[(0 * 16 + l15) * GQ + g];
        float w1 = fcg_w[(1 * 16 + l15) * GQ + g];
        float w2 = fcg_w[(2 * 16 + l15) * GQ + g];
        float w3 = fcg_w[(3 * 16 + l15) * GQ + g];
        #pragma unroll
        for (int reg = 0; reg < 4; ++reg) {
            float v = y[0][reg] * w0 + y[1][reg] * w1 + y[2][reg] * w2 + y[3][reg] * w3;
            v += __shfl_xor(v, 1, 64);
            v += __shfl_xor(v, 2, 64);
            v += __shfl_xor(v, 4, 64);
            v += __shfl_xor(v, 8, 64);
            sg[g][reg] = v + fcg_b[g];
        }
    }
    #pragma unroll
    for (int reg = 0; reg < 4; ++reg) {
        if (l15 == reg) {
            int row = rowbase + l4 * 4 + reg;
            if (row < NUQ) {
                float s0 = sg[0][reg], s1 = sg[1][reg], s2 = sg[2][reg], s3 = sg[3][reg];
                float m = fmaxf(fmaxf(s0, s1), fmaxf(s2, s3));
                int cnt = 0, arg = 0;
                if (m - s0 < EPSM) { ++cnt; arg = 0; }
                if (m - s1 < EPSM) { ++cnt; arg = 1; }
                if (m - s2 < EPSM) { ++cnt; arg = 2; }
                if (m - s3 < EPSM) { ++cnt; arg = 3; }
                if (cnt > 1) risky[row] = 1;
                else         mask8[row] = (unsigned char)(1u << arg);
            }
        }
    }
}

// f64 fixup for near-tie rows, from ORIGINAL f32 inputs (decision-exact).
__global__ void fix_risky_kernel(const float* __restrict__ user_emb,
                                 const float* __restrict__ item_emb,
                                 const float* __restrict__ fc_w,
                                 const float* __restrict__ fc_b,
                                 const float* __restrict__ fcg_w,
                                 const float* __restrict__ fcg_b,
                                 const int* __restrict__ ofs,
                                 const uint2* __restrict__ edge_cv,
                                 const unsigned char* __restrict__ risky,
                                 unsigned char* __restrict__ mask8) {
    int wid  = (int)(((size_t)blockIdx.x * blockDim.x + threadIdx.x) >> 6);
    int lane = threadIdx.x & 63;
    if (wid >= NUQ) return;
    int r = wid;
    if (!risky[r]) return;
    const float* ib = item_emb - (size_t)NUQ * DQ;
    int beg = ofs[r], end = ofs[r + 1];
    double a = 0.0;
    for (int i = beg; i < end; ++i) {
        uint2 cv = edge_cv[i];
        int c = (int)cv.x;
        const float* p = ((c < NUQ) ? user_emb : ib) + (size_t)c * DQ;
        a += (double)__uint_as_float(cv.y) * (double)p[lane];
    }
    double x = (double)user_emb[(size_t)r * DQ + lane] + a;
    double t = (double)fc_b[lane];
    for (int k = 0; k < DQ; ++k)
        t += __shfl(x, k, 64) * (double)fc_w[k * DQ + lane];
    t = (t > 0.0) ? t : 0.01 * t;
    double sg[GQ];
    #pragma unroll
    for (int g = 0; g < GQ; ++g) {
        double v2 = t * (double)fcg_w[lane * GQ + g];
        #pragma unroll
        for (int off = 32; off > 0; off >>= 1) v2 += __shfl_xor(v2, off, 64);
        sg[g] = v2 + (double)fcg_b[g];
    }
    double m = fmax(fmax(sg[0], sg[1]), fmax(sg[2], sg[3]));
    unsigned bits = 0;
    #pragma unroll
    for (int g = 0; g < GQ; ++g) if (sg[g] == m) bits |= (1u << g);
    if (lane == 0) mask8[r] = (unsigned char)bits;
}

// ---------------------------------------------------------------------------
// Layer 1 for needed rows, gathering bf16 side. emb4 layout [N][4][64] f32.
__global__ void layer1_kernel(const int* __restrict__ ofs,
                              const uint2* __restrict__ edge_cv,
                              const unsigned char* __restrict__ mask8,
                              const unsigned char* __restrict__ needed,
                              const unsigned int* __restrict__ sideh,
                              float* __restrict__ emb4) {
    int wid  = (int)(((size_t)blockIdx.x * blockDim.x + threadIdx.x) >> 6);
    int lane = threadIdx.x & 63;
    if (wid >= NQ) return;
    int r = wid;
    if (!needed[r]) return;
    unsigned mr = mask8[r];
    int j = lane & 31, h = lane >> 5;
    int beg = ofs[r], end = ofs[r + 1];
    bool single = (mr & (mr - 1u)) == 0u;

    if (single) {
        float acc0 = 0.f, acc1 = 0.f;
        for (int base = beg; base < end; base += 64) {
            int n = end - base; if (n > 64) n = 64;
            int n1 = n - 1;
            uint2 cv = edge_cv[base + (lane < n ? lane : n1)];
            int   cc = (int)cv.x;
            float vv = __uint_as_float(cv.y);
            int pack = cc | ((int)(mr & (unsigned)mask8[cc]) << 20);
            int npair = (n + 1) >> 1;
            for (int p = 0; p < npair; p += 4) {
                int i0 = 2 * p + h, i1 = i0 + 2, i2 = i0 + 4, i3 = i0 + 6;
                int k0 = (i0 <= n1) ? i0 : n1, k1 = (i1 <= n1) ? i1 : n1;
                int k2 = (i2 <= n1) ? i2 : n1, k3 = (i3 <= n1) ? i3 : n1;
                int w0 = __shfl(pack, k0, 64), w1 = __shfl(pack, k1, 64);
                int w2 = __shfl(pack, k2, 64), w3 = __shfl(pack, k3, 64);
                float v0 = __shfl(vv, k0, 64), v1 = __shfl(vv, k1, 64);
                float v2 = __shfl(vv, k2, 64), v3 = __shfl(vv, k3, 64);
                if (i0 > n1 || !((unsigned)w0 >> 20)) v0 = 0.f;
                if (i1 > n1 || !((unsigned)w1 >> 20)) v1 = 0.f;
                if (i2 > n1 || !((unsigned)w2 >> 20)) v2 = 0.f;
                if (i3 > n1 || !((unsigned)w3 >> 20)) v3 = 0.f;
                unsigned e0 = sideh[((size_t)(w0 & 0xFFFFF) << 5) + j];
                unsigned e1 = sideh[((size_t)(w1 & 0xFFFFF) << 5) + j];
                unsigned e2 = sideh[((size_t)(w2 & 0xFFFFF) << 5) + j];
                unsigned e3 = sideh[((size_t)(w3 & 0xFFFFF) << 5) + j];
                acc0 += v0 * bflo(e0);  acc1 += v0 * bfhi(e0);
                acc0 += v1 * bflo(e1);  acc1 += v1 * bfhi(e1);
                acc0 += v2 * bflo(e2);  acc1 += v2 * bfhi(e2);
                acc0 += v3 * bflo(e3);  acc1 += v3 * bfhi(e3);
            }
        }
        acc0 += __shfl_xor(acc0, 32, 64);
        acc1 += __shfl_xor(acc1, 32, 64);
        int p = __ffs((int)mr) - 1;
        if (lane < 32) {
            float2* dst = (float2*)(emb4 + (((size_t)r * GQ + p) << 6));
            dst[j] = make_float2(acc0, acc1);
        }
    } else {
        float b0 = 0.f, b1 = 0.f, b2 = 0.f, b3 = 0.f;   // dim 2j, planes 0-3
        float d0 = 0.f, d1 = 0.f, d2 = 0.f, d3 = 0.f;   // dim 2j+1
        for (int base = beg; base < end; base += 64) {
            int n = end - base; if (n > 64) n = 64;
            int n1 = n - 1;
            uint2 cv = edge_cv[base + (lane < n ? lane : n1)];
            int   cc = (int)cv.x;
            float vv = __uint_as_float(cv.y);
            int pack = cc | ((int)(mr & (unsigned)mask8[cc]) << 20);
            int npair = (n + 1) >> 1;
            for (int p = 0; p < npair; p += 2) {
                int ia = 2 * p + h, ibx = ia + 2;
                int ka = (ia <= n1) ? ia : n1, kb = (ibx <= n1) ? ibx : n1;
                int wa = __shfl(pack, ka, 64), wb = __shfl(pack, kb, 64);
                float va = __shfl(vv, ka, 64), vb = __shfl(vv, kb, 64);
                if (ia > n1)  va = 0.f;
                if (ibx > n1) vb = 0.f;
                unsigned ea = sideh[((size_t)(wa & 0xFFFFF) << 5) + j];
                unsigned eb = sideh[((size_t)(wb & 0xFFFFF) << 5) + j];
                unsigned ma = (unsigned)wa >> 20, mb = (unsigned)wb >> 20;
                float fa0 = va * bflo(ea), fa1 = va * bfhi(ea);
                float fb0 = vb * bflo(eb), fb1 = vb * bfhi(eb);
                b0 += (ma & 1u) ? fa0 : 0.f;  d0 += (ma & 1u) ? fa1 : 0.f;
                b1 += (ma & 2u) ? fa0 : 0.f;  d1 += (ma & 2u) ? fa1 : 0.f;
                b2 += (ma & 4u) ? fa0 : 0.f;  d2 += (ma & 4u) ? fa1 : 0.f;
                b3 += (ma & 8u) ? fa0 : 0.f;  d3 += (ma & 8u) ? fa1 : 0.f;
                b0 += (mb & 1u) ? fb0 : 0.f;  d0 += (mb & 1u) ? fb1 : 0.f;
                b1 += (mb & 2u) ? fb0 : 0.f;  d1 += (mb & 2u) ? fb1 : 0.f;
                b2 += (mb & 4u) ? fb0 : 0.f;  d2 += (mb & 4u) ? fb1 : 0.f;
                b3 += (mb & 8u) ? fb0 : 0.f;  d3 += (mb & 8u) ? fb1 : 0.f;
            }
        }
        b0 += __shfl_xor(b0, 32, 64);  d0 += __shfl_xor(d0, 32, 64);
        b1 += __shfl_xor(b1, 32, 64);  d1 += __shfl_xor(d1, 32, 64);
        b2 += __shfl_xor(b2, 32, 64);  d2 += __shfl_xor(d2, 32, 64);
        b3 += __shfl_xor(b3, 32, 64);  d3 += __shfl_xor(d3, 32, 64);
        if (lane < 32) {
            float2* dst = (float2*)(emb4 + (((size_t)r * GQ) << 6));
            dst[j]      = make_float2(b0, d0);
            dst[j + 32] = make_float2(b1, d1);
            dst[j + 64] = make_float2(b2, d2);
            dst[j + 96] = make_float2(b3, d3);
        }
    }
}

// ---------------------------------------------------------------------------
// Fused layer2 + gamma, sampled rows only.
__device__ __forceinline__ float l2_row(int r, int lane, unsigned mr,
                                        const int* __restrict__ ofs,
                                        const uint2* __restrict__ edge_cv,
                                        const unsigned char* __restrict__ mask8,
                                        const float* __restrict__ emb4) {
    float sum = 0.f;
    int beg = ofs[r], end = ofs[r + 1];
    for (int base = beg; base < end; base += 64) {
        int n = end - base; if (n > 64) n = 64;
        int n1 = n - 1;
        uint2 cv = edge_cv[base + (lane < n ? lane : n1)];
        int   cc = (int)cv.x;
        float vv = __uint_as_float(cv.y);
        int pack = cc | ((int)(mr & (unsigned)mask8[cc]) << 20);
        for (int e = 0; e < n; ++e) {
            int w = __shfl(pack, e, 64);
            unsigned mb = ((unsigned)w >> 20) & 0xFu;
            if (!mb) continue;
            float v = __shfl(vv, e, 64);
            size_t co = (size_t)(w & 0xFFFFF) * (GQ * DQ) + lane;
            if (mb == 0xFu) {
                sum += v * (emb4[co] + emb4[co + DQ] + emb4[co + 2 * DQ] + emb4[co + 3 * DQ]);
            } else if ((mb & (mb - 1u)) == 0u) {
                sum += v * emb4[co + ((__ffs((int)mb) - 1) << 6)];
            } else {
                #pragma unroll
                for (int g = 0; g < GQ; ++g)
                    if ((mb >> g) & 1u) sum += v * emb4[co + (g << 6)];
            }
        }
    }
    return sum;
}

__global__ void gamma_kernel(const int* __restrict__ ofs,
                             const uint2* __restrict__ edge_cv,
                             const unsigned char* __restrict__ mask8,
                             const float* __restrict__ side32,
                             const float* __restrict__ emb4,
                             const int* __restrict__ users,
                             const int* __restrict__ items,
                             float* __restrict__ out, int B) {
    int wid  = (int)(((size_t)blockIdx.x * blockDim.x + threadIdx.x) >> 6);
    int lane = threadIdx.x & 63;
    if (wid >= B) return;
    int u  = users[wid];
    int it = NUQ + items[wid];
    unsigned mu = mask8[u];
    size_t uo = (size_t)u * GQ * DQ + lane;
    size_t io = (size_t)it * GQ * DQ + lane;
    float baseu = 0.f;
    #pragma unroll
    for (int g = 0; g < GQ; ++g)
        if ((mu >> g) & 1u) baseu += emb4[uo + (g << 6)];
    float basei = emb4[io] + emb4[io + DQ] + emb4[io + 2 * DQ] + emb4[io + 3 * DQ];
    float su = side32[(size_t)u * DQ + lane];
    float si = side32[(size_t)it * DQ + lane];
    float fu = 4.f * su + baseu + l2_row(u, lane, mu, ofs, edge_cv, mask8, emb4);
    float fi = 4.f * si + basei + l2_row(it, lane, 0xFu, ofs, edge_cv, mask8, emb4);
    float p = fu * fi;
    #pragma unroll
    for (int off = 32; off > 0; off >>= 1) p += __shfl_xor(p, off, 64);
    if (lane == 0) out[wid] = 0.04f * p;   // 0.2^2
}

// ---------------------------------------------------------------------------
extern "C" void kernel_launch(void* const* d_in, const int* in_sizes, int n_in,
                              void* d_out, int out_size, void* d_ws, size_t ws_size,
                              hipStream_t stream) {
    const float* user_emb = (const float*)d_in[0];
    const float* item_emb = (const float*)d_in[1];
    const float* fc_w     = (const float*)d_in[2];
    const float* fc_b     = (const float*)d_in[3];
    const float* fcg_w    = (const float*)d_in[4];
    const float* fcg_b    = (const float*)d_in[5];
    const float* vals     = (const float*)d_in[6];
    const int*   rows     = (const int*)d_in[7];
    const int*   cols     = (const int*)d_in[8];
    const int*   users    = (const int*)d_in[9];
    const int*   items    = (const int*)d_in[10];
    const int nnz = in_sizes[6];
    const int B   = in_sizes[9];
    float* out = (float*)d_out;

    const size_t ND = (size_t)NQ * DQ;

    char* ws = (char*)d_ws;
    size_t off = 0;
    float* emb4 = (float*)(ws + off); off += 4 * ND * sizeof(float);           // 153.6 MB
    unsigned int* embh  = (unsigned int*)(ws + off); off += ND * 2;            //  19.2 MB
    unsigned int* sideh = (unsigned int*)(ws + off); off += ND * 2;            //  19.2 MB
    float* side32 = (float*)(ws + off); off += ND * sizeof(float);             //  38.4 MB
    uint2* edge_cv = (uint2*)(ws + off); off += (size_t)nnz * 8;               //  16.0 MB
    int* row_ofs  = (int*)(ws + off); off += ((size_t)(NQ + 1) * 4 + 255) / 256 * 256;
    int* bsum     = (int*)(ws + off); off += ((size_t)SCAN_NB * 4 + 255) / 256 * 256;
    unsigned int* fcfrag = (unsigned int*)(ws + off); off += 2 * FRAGU * 4;    //  16 KB
    // contiguous zero-init block: row_cnt, row_fill, needed/risky bytes
    char* zblock = ws + off;
    int* row_cnt  = (int*)(ws + off); off += (size_t)NQ * 4;
    int* row_fill = (int*)(ws + off); off += (size_t)NQ * 4;
    unsigned char* needed = (unsigned char*)(ws + off); off += ((size_t)NQ + 255) / 256 * 256;
    unsigned char* risky  = (unsigned char*)(ws + off); off += ((size_t)NUQ + 255) / 256 * 256;
    size_t zbytes = (size_t)(ws + off - zblock);
    unsigned char* mask8  = (unsigned char*)(ws + off); off += ((size_t)NQ + 255) / 256 * 256;

    // Radix-build temporaries ALIAS emb4 (emb4 not live during CSR build):
    const int NB2 = (nnz + 255) / 256;
    const int M   = NPART * NB2;
    const int M2  = (M + 255) / 256;
    uint2* tmp_cv  = (uint2*)emb4;                                      // nnz*8
    int*   tmp_row = (int*)((char*)emb4 + (size_t)nnz * 8);             // nnz*4
    int*   bhist   = (int*)((char*)emb4 + ((size_t)nnz * 12 + 255) / 256 * 256); // (M+1)*4
    int*   bsum2   = bhist + ((M + 64) / 64 * 64);                      // M2*4

    // --- CSR build: row offsets + zero-atomic radix scatter + final place ---
    hipMemsetAsync(zblock, 0, zbytes, stream);
    hist_kernel<<<(nnz + 255) / 256, 256, 0, stream>>>(rows, row_cnt, nnz);
    scanA_kernel<<<SCAN_NB, 256, 0, stream>>>(row_cnt, row_ofs, bsum, NQ);
    scanB_kernel<<<1, 64, 0, stream>>>(bsum);
    scanC_kernel<<<SCAN_NB, 256, 0, stream>>>(row_ofs, bsum, NQ, nnz);

    hist2_kernel<<<NB2, 256, 0, stream>>>(rows, bhist, nnz, NB2);
    scanA_kernel<<<M2, 256, 0, stream>>>(bhist, bhist, bsum2, M);
    scanB2_kernel<<<1, 64, 0, stream>>>(bsum2, M2);
    scanC_kernel<<<M2, 256, 0, stream>>>(bhist, bsum2, M, nnz);
    scatter2_kernel<<<NB2, 256, 0, stream>>>(rows, cols, vals, bhist,
                                             tmp_cv, tmp_row, nnz, NB2);
    final_scatter<<<NB2, 256, 0, stream>>>(tmp_cv, tmp_row, row_ofs, row_fill,
                                           edge_cv, nnz);

    conv_emb_kernel<<<(int)((ND / 2 + 255) / 256), 256, 0, stream>>>(
        user_emb, item_emb, embh);
    fc_frag_kernel<<<8, 256, 0, stream>>>(fc_w, fcfrag);
    mark_needed<<<(2 * B * 64 + 255) / 256, 256, 0, stream>>>(
        users, items, row_ofs, edge_cv, needed, B);

    // --- side SpMM (all rows) ---
    const int row_blocks = (NQ * 64 + 255) / 256;   // 4 waves/block
    spmm_side_kernel<<<row_blocks, 256, 0, stream>>>(embh, row_ofs, edge_cv,
                                                     sideh, side32, mask8);

    // --- user scores via bf16x3 MFMA -> masks (+risky) ---
    scores_mfma_kernel<<<(NUQ + 63) / 64, 256, 0, stream>>>(
        user_emb, side32, fcfrag, fc_b, fcg_w, fcg_b, mask8, risky);
    fix_risky_kernel<<<(NUQ * 64 + 255) / 256, 256, 0, stream>>>(
        user_emb, item_emb, fc_w, fc_b, fcg_w, fcg_b,
        row_ofs, edge_cv, risky, mask8);

    // --- layer 1 (needed rows only) ---
    layer1_kernel<<<row_blocks, 256, 0, stream>>>(row_ofs, edge_cv, mask8,
                                                  needed, sideh, emb4);

    // --- fused layer2 + gamma (sampled rows only) ---
    gamma_kernel<<<((size_t)B * 64 + 255) / 256, 256, 0, stream>>>(
        row_ofs, edge_cv, mask8, side32, emb4, users, items, out, B);
}

// Round 16
// 389.314 us; speedup vs baseline: 1.4037x; 1.1912x over previous
//
#include <hip/hip_runtime.h>
#include <hip/hip_bf16.h>

// LightGCN_27384711480190 — r16: revert scatter to r8 single-pass (the radix
// pipeline r9-r15 measured as a wash); keep bf16x3 scores + f32 side + 8-deep
// gather MLP; layer1 single-group path widened to 8-deep.
#define NUQ 100000   // users
#define NIQ 50000    // items
#define NQ  150000   // N = NU + NI
#define DQ  64       // embedding dim (== wavefront)
#define GQ  4        // groups
#define EPSM 1e-2f   // argmax margin; bf16x3 score err ~1e-3 tail

#define SCAN_NB  ((NQ + 255) / 256)
#define SCANB_PER ((SCAN_NB + 63) / 64)
#define FRAGU (8 * 64 * 4)                           // uints per fragment block

typedef __attribute__((ext_vector_type(8))) short bf16x8;
typedef __attribute__((ext_vector_type(4))) float f32x4;
typedef __attribute__((ext_vector_type(4))) unsigned int uint4v;

__device__ __forceinline__ unsigned f2bf(float f) {   // RNE f32 -> bf16 bits
    unsigned u = __float_as_uint(f);
    return (u + 0x7FFFu + ((u >> 16) & 1u)) >> 16;
}
__device__ __forceinline__ float bflo(unsigned w) { return __uint_as_float(w << 16); }
__device__ __forceinline__ float bfhi(unsigned w) { return __uint_as_float(w & 0xFFFF0000u); }

// ---------------------------------------------------------------------------
// CSR build: histogram -> exclusive scan -> single-pass scatter (r8 form;
// fill atomics, replay-stable empirically across r7/r8/r10-r12/r15).
__global__ void hist_kernel(const int* __restrict__ rows, int* __restrict__ cnt,
                            int nnz) {
    int e = blockIdx.x * blockDim.x + threadIdx.x;
    if (e < nnz) atomicAdd(&cnt[rows[e]], 1);
}

__global__ void scanA_kernel(const int* __restrict__ cnt, int* __restrict__ ofs,
                             int* __restrict__ bsum, int n) {
    int i = blockIdx.x * 256 + threadIdx.x;
    int v = (i < n) ? cnt[i] : 0;
    int lane = threadIdx.x & 63, w = threadIdx.x >> 6;
    int s = v;
    #pragma unroll
    for (int off = 1; off < 64; off <<= 1) {
        int t = __shfl_up(s, off, 64);
        if (lane >= off) s += t;
    }
    __shared__ int wsum[4];
    if (lane == 63) wsum[w] = s;
    __syncthreads();
    int add = 0;
    for (int k = 0; k < w; ++k) add += wsum[k];
    int incl = s + add;
    if (i < n) ofs[i] = incl - v;
    if (threadIdx.x == 255) bsum[blockIdx.x] = incl;
}

__global__ void scanB_kernel(int* __restrict__ bsum) {
    int lane = threadIdx.x;                 // single wave
    int base = lane * SCANB_PER;
    int local[SCANB_PER];
    int s = 0;
    #pragma unroll
    for (int k = 0; k < SCANB_PER; ++k) {
        int idx = base + k;
        int t = (idx < SCAN_NB) ? bsum[idx] : 0;
        local[k] = s;
        s += t;
    }
    int incl = s;
    #pragma unroll
    for (int off = 1; off < 64; off <<= 1) {
        int t = __shfl_up(incl, off, 64);
        if (lane >= off) incl += t;
    }
    int excl = incl - s;
    #pragma unroll
    for (int k = 0; k < SCANB_PER; ++k) {
        int idx = base + k;
        if (idx < SCAN_NB) bsum[idx] = excl + local[k];
    }
}

__global__ void scanC_kernel(int* __restrict__ ofs, const int* __restrict__ bsum,
                             int n, int nnz) {
    int i = blockIdx.x * 256 + threadIdx.x;
    if (i < n) ofs[i] += bsum[blockIdx.x];
    if (i == 0) ofs[n] = nnz;
}

__global__ void scatter_kernel(const int* __restrict__ rows,
                               const int* __restrict__ cols,
                               const float* __restrict__ vals,
                               const int* __restrict__ ofs,
                               int* __restrict__ fill,
                               uint2* __restrict__ edge_cv, int nnz) {
    int e = blockIdx.x * blockDim.x + threadIdx.x;
    if (e >= nnz) return;
    int r = rows[e];
    int pos = ofs[r] + atomicAdd(&fill[r], 1);
    edge_cv[pos] = make_uint2((unsigned)cols[e], __float_as_uint(vals[e]));
}

// all_emb -> bf16 table [N][64] (stored as uint[N][32], 2 dims per uint).
__global__ void conv_emb_kernel(const float* __restrict__ user_emb,
                                const float* __restrict__ item_emb,
                                unsigned int* __restrict__ embh) {
    size_t i = (size_t)blockIdx.x * blockDim.x + threadIdx.x;
    if (i >= (size_t)NQ * 32) return;
    size_t node = i >> 5; int j = (int)(i & 31);
    const float* src = (node < NUQ) ? (user_emb + node * DQ)
                                    : (item_emb + (node - NUQ) * DQ);
    embh[i] = f2bf(src[2 * j]) | (f2bf(src[2 * j + 1]) << 16);
}

// fc_w -> bf16 MFMA B-fragments, hi block [0,FRAGU) and lo residual block.
__global__ void fc_frag_kernel(const float* __restrict__ fc_w,
                               unsigned int* __restrict__ fcfrag) {
    int i = blockIdx.x * blockDim.x + threadIdx.x;
    if (i >= FRAGU) return;
    int k = i & 3;
    int l = (i >> 2) & 63;
    int f = i >> 8;
    int t = f >> 1, q = f & 1;
    int col = t * 16 + (l & 15);
    int krow = q * 32 + ((l >> 4) << 3) + 2 * k;
    float w0 = fc_w[krow * DQ + col];
    float w1 = fc_w[(krow + 1) * DQ + col];
    unsigned h0 = f2bf(w0), h1 = f2bf(w1);
    float r0 = w0 - __uint_as_float(h0 << 16);
    float r1 = w1 - __uint_as_float(h1 << 16);
    fcfrag[i]         = h0 | (h1 << 16);
    fcfrag[FRAGU + i] = f2bf(r0) | (f2bf(r1) << 16);
}

// Mark nodes whose layer-1 planes are ever read.
__global__ void mark_needed(const int* __restrict__ users,
                            const int* __restrict__ items,
                            const int* __restrict__ ofs,
                            const uint2* __restrict__ edge_cv,
                            unsigned char* __restrict__ needed, int B) {
    int wid  = (int)(((size_t)blockIdx.x * blockDim.x + threadIdx.x) >> 6);
    int lane = threadIdx.x & 63;
    if (wid >= 2 * B) return;
    int r = (wid < B) ? users[wid] : (NUQ + items[wid - B]);
    if (lane == 0) needed[r] = 1;
    int beg = ofs[r], end = ofs[r + 1];
    for (int i = beg + lane; i < end; i += 64) needed[(int)edge_cv[i].x] = 1;
}

// ---------------------------------------------------------------------------
// SpMM-only side pass. Half-split lanes, 8 gathers in flight.
__global__ void spmm_side_kernel(const unsigned int* __restrict__ embh,
                                 const int* __restrict__ ofs,
                                 const uint2* __restrict__ edge_cv,
                                 unsigned int* __restrict__ sideh,
                                 float* __restrict__ side32,
                                 unsigned char* __restrict__ mask8) {
    int wid  = (int)(((size_t)blockIdx.x * blockDim.x + threadIdx.x) >> 6);
    int lane = threadIdx.x & 63;
    if (wid >= NQ) return;
    int r = wid;
    int j = lane & 31, h = lane >> 5;
    int beg = ofs[r], end = ofs[r + 1];
    float acc0 = 0.f, acc1 = 0.f;     // dims (2j, 2j+1), this half's edges
    for (int base = beg; base < end; base += 64) {
        int n = end - base; if (n > 64) n = 64;
        int n1 = n - 1;
        uint2 cv = edge_cv[base + (lane < n ? lane : n1)];
        int   cc = (int)cv.x;
        float vv = __uint_as_float(cv.y);
        int npair = (n + 1) >> 1;
        for (int p = 0; p < npair; p += 8) {
            int   ccc[8];
            float vvv[8];
            #pragma unroll
            for (int u = 0; u < 8; ++u) {
                int iu = 2 * (p + u) + h;
                int ku = (iu <= n1) ? iu : n1;
                ccc[u] = __shfl(cc, ku, 64);
                float vu = __shfl(vv, ku, 64);
                vvv[u] = (iu > n1) ? 0.f : vu;
            }
            unsigned ww[8];
            #pragma unroll
            for (int u = 0; u < 8; ++u)
                ww[u] = embh[((size_t)ccc[u] << 5) + j];
            #pragma unroll
            for (int u = 0; u < 8; ++u) {
                acc0 += vvv[u] * bflo(ww[u]);
                acc1 += vvv[u] * bfhi(ww[u]);
            }
        }
    }
    acc0 += __shfl_xor(acc0, 32, 64);
    acc1 += __shfl_xor(acc1, 32, 64);
    if (lane < 32) {
        sideh[((size_t)r << 5) + j] = f2bf(acc0) | (f2bf(acc1) << 16);
        ((float2*)(side32 + ((size_t)r << 6)))[j] = make_float2(acc0, acc1);
    }
    if (r >= NUQ && lane == 0) mask8[r] = 0xFu;   // items: all groups
}

// ---------------------------------------------------------------------------
// Scores via bf16x3 error-compensated MFMA: x@W ~= xh@Wh + xl@Wh + xh@Wl.
__global__ __launch_bounds__(256) void scores_mfma_kernel(
        const float* __restrict__ user_emb,
        const float* __restrict__ side32,
        const unsigned int* __restrict__ fcfrag,
        const float* __restrict__ fc_b,
        const float* __restrict__ fcg_w,
        const float* __restrict__ fcg_b,
        unsigned char* __restrict__ mask8,
        unsigned char* __restrict__ risky) {
    int lane = threadIdx.x & 63;
    int wave = threadIdx.x >> 6;
    int rowbase = blockIdx.x * 64 + wave * 16;
    if (rowbase >= NUQ) return;
    int l15 = lane & 15, l4 = lane >> 4;

    int arow = rowbase + l15; if (arow >= NUQ) arow = NUQ - 1;
    union { unsigned u[4]; bf16x8 v; } ah[2], al[2];
    #pragma unroll
    for (int q = 0; q < 2; ++q) {
        int k0 = q * 32 + (l4 << 3);
        const float* ue = user_emb + (size_t)arow * DQ + k0;
        const float* sp = side32   + (size_t)arow * DQ + k0;
        #pragma unroll
        for (int kk = 0; kk < 4; ++kk) {
            float x0 = ue[2 * kk]     + sp[2 * kk];
            float x1 = ue[2 * kk + 1] + sp[2 * kk + 1];
            unsigned h0 = f2bf(x0), h1 = f2bf(x1);
            ah[q].u[kk] = h0 | (h1 << 16);
            float r0 = x0 - __uint_as_float(h0 << 16);
            float r1 = x1 - __uint_as_float(h1 << 16);
            al[q].u[kk] = f2bf(r0) | (f2bf(r1) << 16);
        }
    }
    union { uint4v u; bf16x8 v; } bh[8], bl[8];
    const uint4v* bph = (const uint4v*)fcfrag;
    const uint4v* bpl = (const uint4v*)(fcfrag + FRAGU);
    #pragma unroll
    for (int f = 0; f < 8; ++f) { bh[f].u = bph[f * 64 + lane]; bl[f].u = bpl[f * 64 + lane]; }

    float y[4][4];
    #pragma unroll
    for (int t = 0; t < 4; ++t) {
        f32x4 acc = {0.f, 0.f, 0.f, 0.f};
        acc = __builtin_amdgcn_mfma_f32_16x16x32_bf16(ah[0].v, bh[t * 2 + 0].v, acc, 0, 0, 0);
        acc = __builtin_amdgcn_mfma_f32_16x16x32_bf16(ah[1].v, bh[t * 2 + 1].v, acc, 0, 0, 0);
        acc = __builtin_amdgcn_mfma_f32_16x16x32_bf16(al[0].v, bh[t * 2 + 0].v, acc, 0, 0, 0);
        acc = __builtin_amdgcn_mfma_f32_16x16x32_bf16(al[1].v, bh[t * 2 + 1].v, acc, 0, 0, 0);
        acc = __builtin_amdgcn_mfma_f32_16x16x32_bf16(ah[0].v, bl[t * 2 + 0].v, acc, 0, 0, 0);
        acc = __builtin_amdgcn_mfma_f32_16x16x32_bf16(ah[1].v, bl[t * 2 + 1].v, acc, 0, 0, 0);
        float fb = fc_b[t * 16 + l15];
        #pragma unroll
        for (int reg = 0; reg < 4; ++reg) {
            float v = acc[reg] + fb;
            y[t][reg] = (v > 0.f) ? v : 0.01f * v;   // leaky_relu
        }
    }
    float sg[GQ][4];
    #pragma unroll
    for (int g = 0; g < GQ; ++g) {
        float w0 = fcg_w[(0 * 16 + l15) * GQ + g];
        float w1 = fcg_w[(1 * 16 + l15) * GQ + g];
        float w2 = fcg_w[(2 * 16 + l15) * GQ + g];
        float w3 = fcg_w[(3 * 16 + l15) * GQ + g];
        #pragma unroll
        for (int reg = 0; reg < 4; ++reg) {
            float v = y[0][reg] * w0 + y[1][reg] * w1 + y[2][reg] * w2 + y[3][reg] * w3;
            v += __shfl_xor(v, 1, 64);
            v += __shfl_xor(v, 2, 64);
            v += __shfl_xor(v, 4, 64);
            v += __shfl_xor(v, 8, 64);
            sg[g][reg] = v + fcg_b[g];
        }
    }
    #pragma unroll
    for (int reg = 0; reg < 4; ++reg) {
        if (l15 == reg) {
            int row = rowbase + l4 * 4 + reg;
            if (row < NUQ) {
                float s0 = sg[0][reg], s1 = sg[1][reg], s2 = sg[2][reg], s3 = sg[3][reg];
                float m = fmaxf(fmaxf(s0, s1), fmaxf(s2, s3));
                int cnt = 0, arg = 0;
                if (m - s0 < EPSM) { ++cnt; arg = 0; }
                if (m - s1 < EPSM) { ++cnt; arg = 1; }
                if (m - s2 < EPSM) { ++cnt; arg = 2; }
                if (m - s3 < EPSM) { ++cnt; arg = 3; }
                if (cnt > 1) risky[row] = 1;
                else         mask8[row] = (unsigned char)(1u << arg);
            }
        }
    }
}

// f64 fixup for near-tie rows, from ORIGINAL f32 inputs (decision-exact).
__global__ void fix_risky_kernel(const float* __restrict__ user_emb,
                                 const float* __restrict__ item_emb,
                                 const float* __restrict__ fc_w,
                                 const float* __restrict__ fc_b,
                                 const float* __restrict__ fcg_w,
                                 const float* __restrict__ fcg_b,
                                 const int* __restrict__ ofs,
                                 const uint2* __restrict__ edge_cv,
                                 const unsigned char* __restrict__ risky,
                                 unsigned char* __restrict__ mask8) {
    int wid  = (int)(((size_t)blockIdx.x * blockDim.x + threadIdx.x) >> 6);
    int lane = threadIdx.x & 63;
    if (wid >= NUQ) return;
    int r = wid;
    if (!risky[r]) return;
    const float* ib = item_emb - (size_t)NUQ * DQ;
    int beg = ofs[r], end = ofs[r + 1];
    double a = 0.0;
    for (int i = beg; i < end; ++i) {
        uint2 cv = edge_cv[i];
        int c = (int)cv.x;
        const float* p = ((c < NUQ) ? user_emb : ib) + (size_t)c * DQ;
        a += (double)__uint_as_float(cv.y) * (double)p[lane];
    }
    double x = (double)user_emb[(size_t)r * DQ + lane] + a;
    double t = (double)fc_b[lane];
    for (int k = 0; k < DQ; ++k)
        t += __shfl(x, k, 64) * (double)fc_w[k * DQ + lane];
    t = (t > 0.0) ? t : 0.01 * t;
    double sg[GQ];
    #pragma unroll
    for (int g = 0; g < GQ; ++g) {
        double v2 = t * (double)fcg_w[lane * GQ + g];
        #pragma unroll
        for (int off = 32; off > 0; off >>= 1) v2 += __shfl_xor(v2, off, 64);
        sg[g] = v2 + (double)fcg_b[g];
    }
    double m = fmax(fmax(sg[0], sg[1]), fmax(sg[2], sg[3]));
    unsigned bits = 0;
    #pragma unroll
    for (int g = 0; g < GQ; ++g) if (sg[g] == m) bits |= (1u << g);
    if (lane == 0) mask8[r] = (unsigned char)bits;
}

// ---------------------------------------------------------------------------
// Layer 1 for needed rows, gathering bf16 side. emb4 layout [N][4][64] f32.
// Single-group path 8-deep; multi-group (item) path 2-deep.
__global__ void layer1_kernel(const int* __restrict__ ofs,
                              const uint2* __restrict__ edge_cv,
                              const unsigned char* __restrict__ mask8,
                              const unsigned char* __restrict__ needed,
                              const unsigned int* __restrict__ sideh,
                              float* __restrict__ emb4) {
    int wid  = (int)(((size_t)blockIdx.x * blockDim.x + threadIdx.x) >> 6);
    int lane = threadIdx.x & 63;
    if (wid >= NQ) return;
    int r = wid;
    if (!needed[r]) return;
    unsigned mr = mask8[r];
    int j = lane & 31, h = lane >> 5;
    int beg = ofs[r], end = ofs[r + 1];
    bool single = (mr & (mr - 1u)) == 0u;

    if (single) {
        float acc0 = 0.f, acc1 = 0.f;
        for (int base = beg; base < end; base += 64) {
            int n = end - base; if (n > 64) n = 64;
            int n1 = n - 1;
            uint2 cv = edge_cv[base + (lane < n ? lane : n1)];
            int   cc = (int)cv.x;
            float vv = __uint_as_float(cv.y);
            int pack = cc | ((int)(mr & (unsigned)mask8[cc]) << 20);
            int npair = (n + 1) >> 1;
            for (int p = 0; p < npair; p += 8) {
                int   www[8];
                float vvv[8];
                #pragma unroll
                for (int u = 0; u < 8; ++u) {
                    int iu = 2 * (p + u) + h;
                    int ku = (iu <= n1) ? iu : n1;
                    www[u] = __shfl(pack, ku, 64);
                    float vu = __shfl(vv, ku, 64);
                    vvv[u] = (iu > n1 || !((unsigned)www[u] >> 20)) ? 0.f : vu;
                }
                unsigned ee[8];
                #pragma unroll
                for (int u = 0; u < 8; ++u)
                    ee[u] = sideh[((size_t)(www[u] & 0xFFFFF) << 5) + j];
                #pragma unroll
                for (int u = 0; u < 8; ++u) {
                    acc0 += vvv[u] * bflo(ee[u]);
                    acc1 += vvv[u] * bfhi(ee[u]);
                }
            }
        }
        acc0 += __shfl_xor(acc0, 32, 64);
        acc1 += __shfl_xor(acc1, 32, 64);
        int p = __ffs((int)mr) - 1;
        if (lane < 32) {
            float2* dst = (float2*)(emb4 + (((size_t)r * GQ + p) << 6));
            dst[j] = make_float2(acc0, acc1);
        }
    } else {
        float b0 = 0.f, b1 = 0.f, b2 = 0.f, b3 = 0.f;   // dim 2j, planes 0-3
        float d0 = 0.f, d1 = 0.f, d2 = 0.f, d3 = 0.f;   // dim 2j+1
        for (int base = beg; base < end; base += 64) {
            int n = end - base; if (n > 64) n = 64;
            int n1 = n - 1;
            uint2 cv = edge_cv[base + (lane < n ? lane : n1)];
            int   cc = (int)cv.x;
            float vv = __uint_as_float(cv.y);
            int pack = cc | ((int)(mr & (unsigned)mask8[cc]) << 20);
            int npair = (n + 1) >> 1;
            for (int p = 0; p < npair; p += 2) {
                int ia = 2 * p + h, ibx = ia + 2;
                int ka = (ia <= n1) ? ia : n1, kb = (ibx <= n1) ? ibx : n1;
                int wa = __shfl(pack, ka, 64), wb = __shfl(pack, kb, 64);
                float va = __shfl(vv, ka, 64), vb = __shfl(vv, kb, 64);
                if (ia > n1)  va = 0.f;
                if (ibx > n1) vb = 0.f;
                unsigned ea = sideh[((size_t)(wa & 0xFFFFF) << 5) + j];
                unsigned eb = sideh[((size_t)(wb & 0xFFFFF) << 5) + j];
                unsigned ma = (unsigned)wa >> 20, mb = (unsigned)wb >> 20;
                float fa0 = va * bflo(ea), fa1 = va * bfhi(ea);
                float fb0 = vb * bflo(eb), fb1 = vb * bfhi(eb);
                b0 += (ma & 1u) ? fa0 : 0.f;  d0 += (ma & 1u) ? fa1 : 0.f;
                b1 += (ma & 2u) ? fa0 : 0.f;  d1 += (ma & 2u) ? fa1 : 0.f;
                b2 += (ma & 4u) ? fa0 : 0.f;  d2 += (ma & 4u) ? fa1 : 0.f;
                b3 += (ma & 8u) ? fa0 : 0.f;  d3 += (ma & 8u) ? fa1 : 0.f;
                b0 += (mb & 1u) ? fb0 : 0.f;  d0 += (mb & 1u) ? fb1 : 0.f;
                b1 += (mb & 2u) ? fb0 : 0.f;  d1 += (mb & 2u) ? fb1 : 0.f;
                b2 += (mb & 4u) ? fb0 : 0.f;  d2 += (mb & 4u) ? fb1 : 0.f;
                b3 += (mb & 8u) ? fb0 : 0.f;  d3 += (mb & 8u) ? fb1 : 0.f;
            }
        }
        b0 += __shfl_xor(b0, 32, 64);  d0 += __shfl_xor(d0, 32, 64);
        b1 += __shfl_xor(b1, 32, 64);  d1 += __shfl_xor(d1, 32, 64);
        b2 += __shfl_xor(b2, 32, 64);  d2 += __shfl_xor(d2, 32, 64);
        b3 += __shfl_xor(b3, 32, 64);  d3 += __shfl_xor(d3, 32, 64);
        if (lane < 32) {
            float2* dst = (float2*)(emb4 + (((size_t)r * GQ) << 6));
            dst[j]      = make_float2(b0, d0);
            dst[j + 32] = make_float2(b1, d1);
            dst[j + 64] = make_float2(b2, d2);
            dst[j + 96] = make_float2(b3, d3);
        }
    }
}

// ---------------------------------------------------------------------------
// Fused layer2 + gamma, sampled rows only.
__device__ __forceinline__ float l2_row(int r, int lane, unsigned mr,
                                        const int* __restrict__ ofs,
                                        const uint2* __restrict__ edge_cv,
                                        const unsigned char* __restrict__ mask8,
                                        const float* __restrict__ emb4) {
    float sum = 0.f;
    int beg = ofs[r], end = ofs[r + 1];
    for (int base = beg; base < end; base += 64) {
        int n = end - base; if (n > 64) n = 64;
        int n1 = n - 1;
        uint2 cv = edge_cv[base + (lane < n ? lane : n1)];
        int   cc = (int)cv.x;
        float vv = __uint_as_float(cv.y);
        int pack = cc | ((int)(mr & (unsigned)mask8[cc]) << 20);
        for (int e = 0; e < n; ++e) {
            int w = __shfl(pack, e, 64);
            unsigned mb = ((unsigned)w >> 20) & 0xFu;
            if (!mb) continue;
            float v = __shfl(vv, e, 64);
            size_t co = (size_t)(w & 0xFFFFF) * (GQ * DQ) + lane;
            if (mb == 0xFu) {
                sum += v * (emb4[co] + emb4[co + DQ] + emb4[co + 2 * DQ] + emb4[co + 3 * DQ]);
            } else if ((mb & (mb - 1u)) == 0u) {
                sum += v * emb4[co + ((__ffs((int)mb) - 1) << 6)];
            } else {
                #pragma unroll
                for (int g = 0; g < GQ; ++g)
                    if ((mb >> g) & 1u) sum += v * emb4[co + (g << 6)];
            }
        }
    }
    return sum;
}

__global__ void gamma_kernel(const int* __restrict__ ofs,
                             const uint2* __restrict__ edge_cv,
                             const unsigned char* __restrict__ mask8,
                             const float* __restrict__ side32,
                             const float* __restrict__ emb4,
                             const int* __restrict__ users,
                             const int* __restrict__ items,
                             float* __restrict__ out, int B) {
    int wid  = (int)(((size_t)blockIdx.x * blockDim.x + threadIdx.x) >> 6);
    int lane = threadIdx.x & 63;
    if (wid >= B) return;
    int u  = users[wid];
    int it = NUQ + items[wid];
    unsigned mu = mask8[u];
    size_t uo = (size_t)u * GQ * DQ + lane;
    size_t io = (size_t)it * GQ * DQ + lane;
    float baseu = 0.f;
    #pragma unroll
    for (int g = 0; g < GQ; ++g)
        if ((mu >> g) & 1u) baseu += emb4[uo + (g << 6)];
    float basei = emb4[io] + emb4[io + DQ] + emb4[io + 2 * DQ] + emb4[io + 3 * DQ];
    float su = side32[(size_t)u * DQ + lane];
    float si = side32[(size_t)it * DQ + lane];
    float fu = 4.f * su + baseu + l2_row(u, lane, mu, ofs, edge_cv, mask8, emb4);
    float fi = 4.f * si + basei + l2_row(it, lane, 0xFu, ofs, edge_cv, mask8, emb4);
    float p = fu * fi;
    #pragma unroll
    for (int off = 32; off > 0; off >>= 1) p += __shfl_xor(p, off, 64);
    if (lane == 0) out[wid] = 0.04f * p;   // 0.2^2
}

// ---------------------------------------------------------------------------
extern "C" void kernel_launch(void* const* d_in, const int* in_sizes, int n_in,
                              void* d_out, int out_size, void* d_ws, size_t ws_size,
                              hipStream_t stream) {
    const float* user_emb = (const float*)d_in[0];
    const float* item_emb = (const float*)d_in[1];
    const float* fc_w     = (const float*)d_in[2];
    const float* fc_b     = (const float*)d_in[3];
    const float* fcg_w    = (const float*)d_in[4];
    const float* fcg_b    = (const float*)d_in[5];
    const float* vals     = (const float*)d_in[6];
    const int*   rows     = (const int*)d_in[7];
    const int*   cols     = (const int*)d_in[8];
    const int*   users    = (const int*)d_in[9];
    const int*   items    = (const int*)d_in[10];
    const int nnz = in_sizes[6];
    const int B   = in_sizes[9];
    float* out = (float*)d_out;

    const size_t ND = (size_t)NQ * DQ;

    char* ws = (char*)d_ws;
    size_t off = 0;
    float* emb4 = (float*)(ws + off); off += 4 * ND * sizeof(float);           // 153.6 MB
    unsigned int* embh  = (unsigned int*)(ws + off); off += ND * 2;            //  19.2 MB
    unsigned int* sideh = (unsigned int*)(ws + off); off += ND * 2;            //  19.2 MB
    float* side32 = (float*)(ws + off); off += ND * sizeof(float);             //  38.4 MB
    uint2* edge_cv = (uint2*)(ws + off); off += (size_t)nnz * 8;               //  16.0 MB
    int* row_ofs  = (int*)(ws + off); off += ((size_t)(NQ + 1) * 4 + 255) / 256 * 256;
    int* bsum     = (int*)(ws + off); off += ((size_t)SCAN_NB * 4 + 255) / 256 * 256;
    unsigned int* fcfrag = (unsigned int*)(ws + off); off += 2 * FRAGU * 4;    //  16 KB
    // contiguous zero-init block: row_cnt, row_fill, needed/risky bytes
    char* zblock = ws + off;
    int* row_cnt  = (int*)(ws + off); off += (size_t)NQ * 4;
    int* row_fill = (int*)(ws + off); off += (size_t)NQ * 4;
    unsigned char* needed = (unsigned char*)(ws + off); off += ((size_t)NQ + 255) / 256 * 256;
    unsigned char* risky  = (unsigned char*)(ws + off); off += ((size_t)NUQ + 255) / 256 * 256;
    size_t zbytes = (size_t)(ws + off - zblock);
    unsigned char* mask8  = (unsigned char*)(ws + off); off += ((size_t)NQ + 255) / 256 * 256;

    // --- CSR build (r8 single-pass scatter) + bf16 tables + fragments ---
    hipMemsetAsync(zblock, 0, zbytes, stream);
    hist_kernel<<<(nnz + 255) / 256, 256, 0, stream>>>(rows, row_cnt, nnz);
    scanA_kernel<<<SCAN_NB, 256, 0, stream>>>(row_cnt, row_ofs, bsum, NQ);
    scanB_kernel<<<1, 64, 0, stream>>>(bsum);
    scanC_kernel<<<SCAN_NB, 256, 0, stream>>>(row_ofs, bsum, NQ, nnz);
    scatter_kernel<<<(nnz + 255) / 256, 256, 0, stream>>>(rows, cols, vals,
                                                          row_ofs, row_fill,
                                                          edge_cv, nnz);
    conv_emb_kernel<<<(int)((ND / 2 + 255) / 256), 256, 0, stream>>>(
        user_emb, item_emb, embh);
    fc_frag_kernel<<<8, 256, 0, stream>>>(fc_w, fcfrag);
    mark_needed<<<(2 * B * 64 + 255) / 256, 256, 0, stream>>>(
        users, items, row_ofs, edge_cv, needed, B);

    // --- side SpMM (all rows) ---
    const int row_blocks = (NQ * 64 + 255) / 256;   // 4 waves/block
    spmm_side_kernel<<<row_blocks, 256, 0, stream>>>(embh, row_ofs, edge_cv,
                                                     sideh, side32, mask8);

    // --- user scores via bf16x3 MFMA -> masks (+risky) ---
    scores_mfma_kernel<<<(NUQ + 63) / 64, 256, 0, stream>>>(
        user_emb, side32, fcfrag, fc_b, fcg_w, fcg_b, mask8, risky);
    fix_risky_kernel<<<(NUQ * 64 + 255) / 256, 256, 0, stream>>>(
        user_emb, item_emb, fc_w, fc_b, fcg_w, fcg_b,
        row_ofs, edge_cv, risky, mask8);

    // --- layer 1 (needed rows only) ---
    layer1_kernel<<<row_blocks, 256, 0, stream>>>(row_ofs, edge_cv, mask8,
                                                  needed, sideh, emb4);

    // --- fused layer2 + gamma (sampled rows only) ---
    gamma_kernel<<<((size_t)B * 64 + 255) / 256, 256, 0, stream>>>(
        row_ofs, edge_cv, mask8, side32, emb4, users, items, out, B);
}

// Round 17
// 304.391 us; speedup vs baseline: 1.7954x; 1.2790x over previous
//
#include <hip/hip_runtime.h>
#include <hip/hip_bf16.h>

// LightGCN_27384711480190 — r17: rank-in-hist (scatter becomes atomic-free),
// layer1 multi-group path widened to 4-deep. Rest identical to r16 (389 us).
#define NUQ 100000   // users
#define NIQ 50000    // items
#define NQ  150000   // N = NU + NI
#define DQ  64       // embedding dim (== wavefront)
#define GQ  4        // groups
#define EPSM 1e-2f   // argmax margin; bf16x3 score err ~1e-3 tail

#define SCAN_NB  ((NQ + 255) / 256)
#define SCANB_PER ((SCAN_NB + 63) / 64)
#define FRAGU (8 * 64 * 4)                           // uints per fragment block

typedef __attribute__((ext_vector_type(8))) short bf16x8;
typedef __attribute__((ext_vector_type(4))) float f32x4;
typedef __attribute__((ext_vector_type(4))) unsigned int uint4v;

__device__ __forceinline__ unsigned f2bf(float f) {   // RNE f32 -> bf16 bits
    unsigned u = __float_as_uint(f);
    return (u + 0x7FFFu + ((u >> 16) & 1u)) >> 16;
}
__device__ __forceinline__ float bflo(unsigned w) { return __uint_as_float(w << 16); }
__device__ __forceinline__ float bfhi(unsigned w) { return __uint_as_float(w & 0xFFFF0000u); }

// ---------------------------------------------------------------------------
// CSR build. hist also captures each edge's slot rank (atomic result ->
// coalesced store; latency hidden). scatter is then ATOMIC-FREE.
__global__ void hist_kernel(const int* __restrict__ rows, int* __restrict__ cnt,
                            int* __restrict__ rank, int nnz) {
    int e = blockIdx.x * blockDim.x + threadIdx.x;
    if (e < nnz) rank[e] = atomicAdd(&cnt[rows[e]], 1);
}

__global__ void scanA_kernel(const int* __restrict__ cnt, int* __restrict__ ofs,
                             int* __restrict__ bsum, int n) {
    int i = blockIdx.x * 256 + threadIdx.x;
    int v = (i < n) ? cnt[i] : 0;
    int lane = threadIdx.x & 63, w = threadIdx.x >> 6;
    int s = v;
    #pragma unroll
    for (int off = 1; off < 64; off <<= 1) {
        int t = __shfl_up(s, off, 64);
        if (lane >= off) s += t;
    }
    __shared__ int wsum[4];
    if (lane == 63) wsum[w] = s;
    __syncthreads();
    int add = 0;
    for (int k = 0; k < w; ++k) add += wsum[k];
    int incl = s + add;
    if (i < n) ofs[i] = incl - v;
    if (threadIdx.x == 255) bsum[blockIdx.x] = incl;
}

__global__ void scanB_kernel(int* __restrict__ bsum) {
    int lane = threadIdx.x;                 // single wave
    int base = lane * SCANB_PER;
    int local[SCANB_PER];
    int s = 0;
    #pragma unroll
    for (int k = 0; k < SCANB_PER; ++k) {
        int idx = base + k;
        int t = (idx < SCAN_NB) ? bsum[idx] : 0;
        local[k] = s;
        s += t;
    }
    int incl = s;
    #pragma unroll
    for (int off = 1; off < 64; off <<= 1) {
        int t = __shfl_up(incl, off, 64);
        if (lane >= off) incl += t;
    }
    int excl = incl - s;
    #pragma unroll
    for (int k = 0; k < SCANB_PER; ++k) {
        int idx = base + k;
        if (idx < SCAN_NB) bsum[idx] = excl + local[k];
    }
}

__global__ void scanC_kernel(int* __restrict__ ofs, const int* __restrict__ bsum,
                             int n, int nnz) {
    int i = blockIdx.x * 256 + threadIdx.x;
    if (i < n) ofs[i] += bsum[blockIdx.x];
    if (i == 0) ofs[n] = nnz;
}

// Atomic-free placement: pos = ofs[row] + precomputed rank.
__global__ void scatter_kernel(const int* __restrict__ rows,
                               const int* __restrict__ cols,
                               const float* __restrict__ vals,
                               const int* __restrict__ ofs,
                               const int* __restrict__ rank,
                               uint2* __restrict__ edge_cv, int nnz) {
    int e = blockIdx.x * blockDim.x + threadIdx.x;
    if (e >= nnz) return;
    int r = rows[e];
    int pos = ofs[r] + rank[e];
    edge_cv[pos] = make_uint2((unsigned)cols[e], __float_as_uint(vals[e]));
}

// all_emb -> bf16 table [N][64] (stored as uint[N][32], 2 dims per uint).
__global__ void conv_emb_kernel(const float* __restrict__ user_emb,
                                const float* __restrict__ item_emb,
                                unsigned int* __restrict__ embh) {
    size_t i = (size_t)blockIdx.x * blockDim.x + threadIdx.x;
    if (i >= (size_t)NQ * 32) return;
    size_t node = i >> 5; int j = (int)(i & 31);
    const float* src = (node < NUQ) ? (user_emb + node * DQ)
                                    : (item_emb + (node - NUQ) * DQ);
    embh[i] = f2bf(src[2 * j]) | (f2bf(src[2 * j + 1]) << 16);
}

// fc_w -> bf16 MFMA B-fragments, hi block [0,FRAGU) and lo residual block.
__global__ void fc_frag_kernel(const float* __restrict__ fc_w,
                               unsigned int* __restrict__ fcfrag) {
    int i = blockIdx.x * blockDim.x + threadIdx.x;
    if (i >= FRAGU) return;
    int k = i & 3;
    int l = (i >> 2) & 63;
    int f = i >> 8;
    int t = f >> 1, q = f & 1;
    int col = t * 16 + (l & 15);
    int krow = q * 32 + ((l >> 4) << 3) + 2 * k;
    float w0 = fc_w[krow * DQ + col];
    float w1 = fc_w[(krow + 1) * DQ + col];
    unsigned h0 = f2bf(w0), h1 = f2bf(w1);
    float r0 = w0 - __uint_as_float(h0 << 16);
    float r1 = w1 - __uint_as_float(h1 << 16);
    fcfrag[i]         = h0 | (h1 << 16);
    fcfrag[FRAGU + i] = f2bf(r0) | (f2bf(r1) << 16);
}

// Mark nodes whose layer-1 planes are ever read.
__global__ void mark_needed(const int* __restrict__ users,
                            const int* __restrict__ items,
                            const int* __restrict__ ofs,
                            const uint2* __restrict__ edge_cv,
                            unsigned char* __restrict__ needed, int B) {
    int wid  = (int)(((size_t)blockIdx.x * blockDim.x + threadIdx.x) >> 6);
    int lane = threadIdx.x & 63;
    if (wid >= 2 * B) return;
    int r = (wid < B) ? users[wid] : (NUQ + items[wid - B]);
    if (lane == 0) needed[r] = 1;
    int beg = ofs[r], end = ofs[r + 1];
    for (int i = beg + lane; i < end; i += 64) needed[(int)edge_cv[i].x] = 1;
}

// ---------------------------------------------------------------------------
// SpMM-only side pass. Half-split lanes, 8 gathers in flight.
__global__ void spmm_side_kernel(const unsigned int* __restrict__ embh,
                                 const int* __restrict__ ofs,
                                 const uint2* __restrict__ edge_cv,
                                 unsigned int* __restrict__ sideh,
                                 float* __restrict__ side32,
                                 unsigned char* __restrict__ mask8) {
    int wid  = (int)(((size_t)blockIdx.x * blockDim.x + threadIdx.x) >> 6);
    int lane = threadIdx.x & 63;
    if (wid >= NQ) return;
    int r = wid;
    int j = lane & 31, h = lane >> 5;
    int beg = ofs[r], end = ofs[r + 1];
    float acc0 = 0.f, acc1 = 0.f;     // dims (2j, 2j+1), this half's edges
    for (int base = beg; base < end; base += 64) {
        int n = end - base; if (n > 64) n = 64;
        int n1 = n - 1;
        uint2 cv = edge_cv[base + (lane < n ? lane : n1)];
        int   cc = (int)cv.x;
        float vv = __uint_as_float(cv.y);
        int npair = (n + 1) >> 1;
        for (int p = 0; p < npair; p += 8) {
            int   ccc[8];
            float vvv[8];
            #pragma unroll
            for (int u = 0; u < 8; ++u) {
                int iu = 2 * (p + u) + h;
                int ku = (iu <= n1) ? iu : n1;
                ccc[u] = __shfl(cc, ku, 64);
                float vu = __shfl(vv, ku, 64);
                vvv[u] = (iu > n1) ? 0.f : vu;
            }
            unsigned ww[8];
            #pragma unroll
            for (int u = 0; u < 8; ++u)
                ww[u] = embh[((size_t)ccc[u] << 5) + j];
            #pragma unroll
            for (int u = 0; u < 8; ++u) {
                acc0 += vvv[u] * bflo(ww[u]);
                acc1 += vvv[u] * bfhi(ww[u]);
            }
        }
    }
    acc0 += __shfl_xor(acc0, 32, 64);
    acc1 += __shfl_xor(acc1, 32, 64);
    if (lane < 32) {
        sideh[((size_t)r << 5) + j] = f2bf(acc0) | (f2bf(acc1) << 16);
        ((float2*)(side32 + ((size_t)r << 6)))[j] = make_float2(acc0, acc1);
    }
    if (r >= NUQ && lane == 0) mask8[r] = 0xFu;   // items: all groups
}

// ---------------------------------------------------------------------------
// Scores via bf16x3 error-compensated MFMA: x@W ~= xh@Wh + xl@Wh + xh@Wl.
__global__ __launch_bounds__(256) void scores_mfma_kernel(
        const float* __restrict__ user_emb,
        const float* __restrict__ side32,
        const unsigned int* __restrict__ fcfrag,
        const float* __restrict__ fc_b,
        const float* __restrict__ fcg_w,
        const float* __restrict__ fcg_b,
        unsigned char* __restrict__ mask8,
        unsigned char* __restrict__ risky) {
    int lane = threadIdx.x & 63;
    int wave = threadIdx.x >> 6;
    int rowbase = blockIdx.x * 64 + wave * 16;
    if (rowbase >= NUQ) return;
    int l15 = lane & 15, l4 = lane >> 4;

    int arow = rowbase + l15; if (arow >= NUQ) arow = NUQ - 1;
    union { unsigned u[4]; bf16x8 v; } ah[2], al[2];
    #pragma unroll
    for (int q = 0; q < 2; ++q) {
        int k0 = q * 32 + (l4 << 3);
        const float* ue = user_emb + (size_t)arow * DQ + k0;
        const float* sp = side32   + (size_t)arow * DQ + k0;
        #pragma unroll
        for (int kk = 0; kk < 4; ++kk) {
            float x0 = ue[2 * kk]     + sp[2 * kk];
            float x1 = ue[2 * kk + 1] + sp[2 * kk + 1];
            unsigned h0 = f2bf(x0), h1 = f2bf(x1);
            ah[q].u[kk] = h0 | (h1 << 16);
            float r0 = x0 - __uint_as_float(h0 << 16);
            float r1 = x1 - __uint_as_float(h1 << 16);
            al[q].u[kk] = f2bf(r0) | (f2bf(r1) << 16);
        }
    }
    union { uint4v u; bf16x8 v; } bh[8], bl[8];
    const uint4v* bph = (const uint4v*)fcfrag;
    const uint4v* bpl = (const uint4v*)(fcfrag + FRAGU);
    #pragma unroll
    for (int f = 0; f < 8; ++f) { bh[f].u = bph[f * 64 + lane]; bl[f].u = bpl[f * 64 + lane]; }

    float y[4][4];
    #pragma unroll
    for (int t = 0; t < 4; ++t) {
        f32x4 acc = {0.f, 0.f, 0.f, 0.f};
        acc = __builtin_amdgcn_mfma_f32_16x16x32_bf16(ah[0].v, bh[t * 2 + 0].v, acc, 0, 0, 0);
        acc = __builtin_amdgcn_mfma_f32_16x16x32_bf16(ah[1].v, bh[t * 2 + 1].v, acc, 0, 0, 0);
        acc = __builtin_amdgcn_mfma_f32_16x16x32_bf16(al[0].v, bh[t * 2 + 0].v, acc, 0, 0, 0);
        acc = __builtin_amdgcn_mfma_f32_16x16x32_bf16(al[1].v, bh[t * 2 + 1].v, acc, 0, 0, 0);
        acc = __builtin_amdgcn_mfma_f32_16x16x32_bf16(ah[0].v, bl[t * 2 + 0].v, acc, 0, 0, 0);
        acc = __builtin_amdgcn_mfma_f32_16x16x32_bf16(ah[1].v, bl[t * 2 + 1].v, acc, 0, 0, 0);
        float fb = fc_b[t * 16 + l15];
        #pragma unroll
        for (int reg = 0; reg < 4; ++reg) {
            float v = acc[reg] + fb;
            y[t][reg] = (v > 0.f) ? v : 0.01f * v;   // leaky_relu
        }
    }
    float sg[GQ][4];
    #pragma unroll
    for (int g = 0; g < GQ; ++g) {
        float w0 = fcg_w[(0 * 16 + l15) * GQ + g];
        float w1 = fcg_w[(1 * 16 + l15) * GQ + g];
        float w2 = fcg_w[(2 * 16 + l15) * GQ + g];
        float w3 = fcg_w[(3 * 16 + l15) * GQ + g];
        #pragma unroll
        for (int reg = 0; reg < 4; ++reg) {
            float v = y[0][reg] * w0 + y[1][reg] * w1 + y[2][reg] * w2 + y[3][reg] * w3;
            v += __shfl_xor(v, 1, 64);
            v += __shfl_xor(v, 2, 64);
            v += __shfl_xor(v, 4, 64);
            v += __shfl_xor(v, 8, 64);
            sg[g][reg] = v + fcg_b[g];
        }
    }
    #pragma unroll
    for (int reg = 0; reg < 4; ++reg) {
        if (l15 == reg) {
            int row = rowbase + l4 * 4 + reg;
            if (row < NUQ) {
                float s0 = sg[0][reg], s1 = sg[1][reg], s2 = sg[2][reg], s3 = sg[3][reg];
                float m = fmaxf(fmaxf(s0, s1), fmaxf(s2, s3));
                int cnt = 0, arg = 0;
                if (m - s0 < EPSM) { ++cnt; arg = 0; }
                if (m - s1 < EPSM) { ++cnt; arg = 1; }
                if (m - s2 < EPSM) { ++cnt; arg = 2; }
                if (m - s3 < EPSM) { ++cnt; arg = 3; }
                if (cnt > 1) risky[row] = 1;
                else         mask8[row] = (unsigned char)(1u << arg);
            }
        }
    }
}

// f64 fixup for near-tie rows, from ORIGINAL f32 inputs (decision-exact).
__global__ void fix_risky_kernel(const float* __restrict__ user_emb,
                                 const float* __restrict__ item_emb,
                                 const float* __restrict__ fc_w,
                                 const float* __restrict__ fc_b,
                                 const float* __restrict__ fcg_w,
                                 const float* __restrict__ fcg_b,
                                 const int* __restrict__ ofs,
                                 const uint2* __restrict__ edge_cv,
                                 const unsigned char* __restrict__ risky,
                                 unsigned char* __restrict__ mask8) {
    int wid  = (int)(((size_t)blockIdx.x * blockDim.x + threadIdx.x) >> 6);
    int lane = threadIdx.x & 63;
    if (wid >= NUQ) return;
    int r = wid;
    if (!risky[r]) return;
    const float* ib = item_emb - (size_t)NUQ * DQ;
    int beg = ofs[r], end = ofs[r + 1];
    double a = 0.0;
    for (int i = beg; i < end; ++i) {
        uint2 cv = edge_cv[i];
        int c = (int)cv.x;
        const float* p = ((c < NUQ) ? user_emb : ib) + (size_t)c * DQ;
        a += (double)__uint_as_float(cv.y) * (double)p[lane];
    }
    double x = (double)user_emb[(size_t)r * DQ + lane] + a;
    double t = (double)fc_b[lane];
    for (int k = 0; k < DQ; ++k)
        t += __shfl(x, k, 64) * (double)fc_w[k * DQ + lane];
    t = (t > 0.0) ? t : 0.01 * t;
    double sg[GQ];
    #pragma unroll
    for (int g = 0; g < GQ; ++g) {
        double v2 = t * (double)fcg_w[lane * GQ + g];
        #pragma unroll
        for (int off = 32; off > 0; off >>= 1) v2 += __shfl_xor(v2, off, 64);
        sg[g] = v2 + (double)fcg_b[g];
    }
    double m = fmax(fmax(sg[0], sg[1]), fmax(sg[2], sg[3]));
    unsigned bits = 0;
    #pragma unroll
    for (int g = 0; g < GQ; ++g) if (sg[g] == m) bits |= (1u << g);
    if (lane == 0) mask8[r] = (unsigned char)bits;
}

// ---------------------------------------------------------------------------
// Layer 1 for needed rows, gathering bf16 side. emb4 layout [N][4][64] f32.
// Single-group path 8-deep; multi-group (item) path 4-deep.
__global__ void layer1_kernel(const int* __restrict__ ofs,
                              const uint2* __restrict__ edge_cv,
                              const unsigned char* __restrict__ mask8,
                              const unsigned char* __restrict__ needed,
                              const unsigned int* __restrict__ sideh,
                              float* __restrict__ emb4) {
    int wid  = (int)(((size_t)blockIdx.x * blockDim.x + threadIdx.x) >> 6);
    int lane = threadIdx.x & 63;
    if (wid >= NQ) return;
    int r = wid;
    if (!needed[r]) return;
    unsigned mr = mask8[r];
    int j = lane & 31, h = lane >> 5;
    int beg = ofs[r], end = ofs[r + 1];
    bool single = (mr & (mr - 1u)) == 0u;

    if (single) {
        float acc0 = 0.f, acc1 = 0.f;
        for (int base = beg; base < end; base += 64) {
            int n = end - base; if (n > 64) n = 64;
            int n1 = n - 1;
            uint2 cv = edge_cv[base + (lane < n ? lane : n1)];
            int   cc = (int)cv.x;
            float vv = __uint_as_float(cv.y);
            int pack = cc | ((int)(mr & (unsigned)mask8[cc]) << 20);
            int npair = (n + 1) >> 1;
            for (int p = 0; p < npair; p += 8) {
                int   www[8];
                float vvv[8];
                #pragma unroll
                for (int u = 0; u < 8; ++u) {
                    int iu = 2 * (p + u) + h;
                    int ku = (iu <= n1) ? iu : n1;
                    www[u] = __shfl(pack, ku, 64);
                    float vu = __shfl(vv, ku, 64);
                    vvv[u] = (iu > n1 || !((unsigned)www[u] >> 20)) ? 0.f : vu;
                }
                unsigned ee[8];
                #pragma unroll
                for (int u = 0; u < 8; ++u)
                    ee[u] = sideh[((size_t)(www[u] & 0xFFFFF) << 5) + j];
                #pragma unroll
                for (int u = 0; u < 8; ++u) {
                    acc0 += vvv[u] * bflo(ee[u]);
                    acc1 += vvv[u] * bfhi(ee[u]);
                }
            }
        }
        acc0 += __shfl_xor(acc0, 32, 64);
        acc1 += __shfl_xor(acc1, 32, 64);
        int p = __ffs((int)mr) - 1;
        if (lane < 32) {
            float2* dst = (float2*)(emb4 + (((size_t)r * GQ + p) << 6));
            dst[j] = make_float2(acc0, acc1);
        }
    } else {
        float b0 = 0.f, b1 = 0.f, b2 = 0.f, b3 = 0.f;   // dim 2j, planes 0-3
        float d0 = 0.f, d1 = 0.f, d2 = 0.f, d3 = 0.f;   // dim 2j+1
        for (int base = beg; base < end; base += 64) {
            int n = end - base; if (n > 64) n = 64;
            int n1 = n - 1;
            uint2 cv = edge_cv[base + (lane < n ? lane : n1)];
            int   cc = (int)cv.x;
            float vv = __uint_as_float(cv.y);
            int pack = cc | ((int)(mr & (unsigned)mask8[cc]) << 20);
            int npair = (n + 1) >> 1;
            for (int p = 0; p < npair; p += 4) {
                int   www[4];
                float vvv[4];
                #pragma unroll
                for (int u = 0; u < 4; ++u) {
                    int iu = 2 * (p + u) + h;
                    int ku = (iu <= n1) ? iu : n1;
                    www[u] = __shfl(pack, ku, 64);
                    float vu = __shfl(vv, ku, 64);
                    vvv[u] = (iu > n1) ? 0.f : vu;
                }
                unsigned ee[4];
                #pragma unroll
                for (int u = 0; u < 4; ++u)
                    ee[u] = sideh[((size_t)(www[u] & 0xFFFFF) << 5) + j];
                #pragma unroll
                for (int u = 0; u < 4; ++u) {
                    unsigned mb = (unsigned)www[u] >> 20;
                    float f0 = vvv[u] * bflo(ee[u]);
                    float f1 = vvv[u] * bfhi(ee[u]);
                    b0 += (mb & 1u) ? f0 : 0.f;  d0 += (mb & 1u) ? f1 : 0.f;
                    b1 += (mb & 2u) ? f0 : 0.f;  d1 += (mb & 2u) ? f1 : 0.f;
                    b2 += (mb & 4u) ? f0 : 0.f;  d2 += (mb & 4u) ? f1 : 0.f;
                    b3 += (mb & 8u) ? f0 : 0.f;  d3 += (mb & 8u) ? f1 : 0.f;
                }
            }
        }
        b0 += __shfl_xor(b0, 32, 64);  d0 += __shfl_xor(d0, 32, 64);
        b1 += __shfl_xor(b1, 32, 64);  d1 += __shfl_xor(d1, 32, 64);
        b2 += __shfl_xor(b2, 32, 64);  d2 += __shfl_xor(d2, 32, 64);
        b3 += __shfl_xor(b3, 32, 64);  d3 += __shfl_xor(d3, 32, 64);
        if (lane < 32) {
            float2* dst = (float2*)(emb4 + (((size_t)r * GQ) << 6));
            dst[j]      = make_float2(b0, d0);
            dst[j + 32] = make_float2(b1, d1);
            dst[j + 64] = make_float2(b2, d2);
            dst[j + 96] = make_float2(b3, d3);
        }
    }
}

// ---------------------------------------------------------------------------
// Fused layer2 + gamma, sampled rows only.
__device__ __forceinline__ float l2_row(int r, int lane, unsigned mr,
                                        const int* __restrict__ ofs,
                                        const uint2* __restrict__ edge_cv,
                                        const unsigned char* __restrict__ mask8,
                                        const float* __restrict__ emb4) {
    float sum = 0.f;
    int beg = ofs[r], end = ofs[r + 1];
    for (int base = beg; base < end; base += 64) {
        int n = end - base; if (n > 64) n = 64;
        int n1 = n - 1;
        uint2 cv = edge_cv[base + (lane < n ? lane : n1)];
        int   cc = (int)cv.x;
        float vv = __uint_as_float(cv.y);
        int pack = cc | ((int)(mr & (unsigned)mask8[cc]) << 20);
        for (int e = 0; e < n; ++e) {
            int w = __shfl(pack, e, 64);
            unsigned mb = ((unsigned)w >> 20) & 0xFu;
            if (!mb) continue;
            float v = __shfl(vv, e, 64);
            size_t co = (size_t)(w & 0xFFFFF) * (GQ * DQ) + lane;
            if (mb == 0xFu) {
                sum += v * (emb4[co] + emb4[co + DQ] + emb4[co + 2 * DQ] + emb4[co + 3 * DQ]);
            } else if ((mb & (mb - 1u)) == 0u) {
                sum += v * emb4[co + ((__ffs((int)mb) - 1) << 6)];
            } else {
                #pragma unroll
                for (int g = 0; g < GQ; ++g)
                    if ((mb >> g) & 1u) sum += v * emb4[co + (g << 6)];
            }
        }
    }
    return sum;
}

__global__ void gamma_kernel(const int* __restrict__ ofs,
                             const uint2* __restrict__ edge_cv,
                             const unsigned char* __restrict__ mask8,
                             const float* __restrict__ side32,
                             const float* __restrict__ emb4,
                             const int* __restrict__ users,
                             const int* __restrict__ items,
                             float* __restrict__ out, int B) {
    int wid  = (int)(((size_t)blockIdx.x * blockDim.x + threadIdx.x) >> 6);
    int lane = threadIdx.x & 63;
    if (wid >= B) return;
    int u  = users[wid];
    int it = NUQ + items[wid];
    unsigned mu = mask8[u];
    size_t uo = (size_t)u * GQ * DQ + lane;
    size_t io = (size_t)it * GQ * DQ + lane;
    float baseu = 0.f;
    #pragma unroll
    for (int g = 0; g < GQ; ++g)
        if ((mu >> g) & 1u) baseu += emb4[uo + (g << 6)];
    float basei = emb4[io] + emb4[io + DQ] + emb4[io + 2 * DQ] + emb4[io + 3 * DQ];
    float su = side32[(size_t)u * DQ + lane];
    float si = side32[(size_t)it * DQ + lane];
    float fu = 4.f * su + baseu + l2_row(u, lane, mu, ofs, edge_cv, mask8, emb4);
    float fi = 4.f * si + basei + l2_row(it, lane, 0xFu, ofs, edge_cv, mask8, emb4);
    float p = fu * fi;
    #pragma unroll
    for (int off = 32; off > 0; off >>= 1) p += __shfl_xor(p, off, 64);
    if (lane == 0) out[wid] = 0.04f * p;   // 0.2^2
}

// ---------------------------------------------------------------------------
extern "C" void kernel_launch(void* const* d_in, const int* in_sizes, int n_in,
                              void* d_out, int out_size, void* d_ws, size_t ws_size,
                              hipStream_t stream) {
    const float* user_emb = (const float*)d_in[0];
    const float* item_emb = (const float*)d_in[1];
    const float* fc_w     = (const float*)d_in[2];
    const float* fc_b     = (const float*)d_in[3];
    const float* fcg_w    = (const float*)d_in[4];
    const float* fcg_b    = (const float*)d_in[5];
    const float* vals     = (const float*)d_in[6];
    const int*   rows     = (const int*)d_in[7];
    const int*   cols     = (const int*)d_in[8];
    const int*   users    = (const int*)d_in[9];
    const int*   items    = (const int*)d_in[10];
    const int nnz = in_sizes[6];
    const int B   = in_sizes[9];
    float* out = (float*)d_out;

    const size_t ND = (size_t)NQ * DQ;

    char* ws = (char*)d_ws;
    size_t off = 0;
    float* emb4 = (float*)(ws + off); off += 4 * ND * sizeof(float);           // 153.6 MB
    unsigned int* embh  = (unsigned int*)(ws + off); off += ND * 2;            //  19.2 MB
    unsigned int* sideh = (unsigned int*)(ws + off); off += ND * 2;            //  19.2 MB
    float* side32 = (float*)(ws + off); off += ND * sizeof(float);             //  38.4 MB
    uint2* edge_cv = (uint2*)(ws + off); off += (size_t)nnz * 8;               //  16.0 MB
    int* rank     = (int*)(ws + off); off += (size_t)nnz * 4;                  //   8.0 MB
    int* row_ofs  = (int*)(ws + off); off += ((size_t)(NQ + 1) * 4 + 255) / 256 * 256;
    int* bsum     = (int*)(ws + off); off += ((size_t)SCAN_NB * 4 + 255) / 256 * 256;
    unsigned int* fcfrag = (unsigned int*)(ws + off); off += 2 * FRAGU * 4;    //  16 KB
    // contiguous zero-init block: row_cnt, needed/risky bytes
    char* zblock = ws + off;
    int* row_cnt  = (int*)(ws + off); off += (size_t)NQ * 4;
    unsigned char* needed = (unsigned char*)(ws + off); off += ((size_t)NQ + 255) / 256 * 256;
    unsigned char* risky  = (unsigned char*)(ws + off); off += ((size_t)NUQ + 255) / 256 * 256;
    size_t zbytes = (size_t)(ws + off - zblock);
    unsigned char* mask8  = (unsigned char*)(ws + off); off += ((size_t)NQ + 255) / 256 * 256;

    // --- CSR build: rank-capturing hist -> scan -> atomic-free scatter ---
    hipMemsetAsync(zblock, 0, zbytes, stream);
    hist_kernel<<<(nnz + 255) / 256, 256, 0, stream>>>(rows, row_cnt, rank, nnz);
    scanA_kernel<<<SCAN_NB, 256, 0, stream>>>(row_cnt, row_ofs, bsum, NQ);
    scanB_kernel<<<1, 64, 0, stream>>>(bsum);
    scanC_kernel<<<SCAN_NB, 256, 0, stream>>>(row_ofs, bsum, NQ, nnz);
    scatter_kernel<<<(nnz + 255) / 256, 256, 0, stream>>>(rows, cols, vals,
                                                          row_ofs, rank,
                                                          edge_cv, nnz);
    conv_emb_kernel<<<(int)((ND / 2 + 255) / 256), 256, 0, stream>>>(
        user_emb, item_emb, embh);
    fc_frag_kernel<<<8, 256, 0, stream>>>(fc_w, fcfrag);
    mark_needed<<<(2 * B * 64 + 255) / 256, 256, 0, stream>>>(
        users, items, row_ofs, edge_cv, needed, B);

    // --- side SpMM (all rows) ---
    const int row_blocks = (NQ * 64 + 255) / 256;   // 4 waves/block
    spmm_side_kernel<<<row_blocks, 256, 0, stream>>>(embh, row_ofs, edge_cv,
                                                     sideh, side32, mask8);

    // --- user scores via bf16x3 MFMA -> masks (+risky) ---
    scores_mfma_kernel<<<(NUQ + 63) / 64, 256, 0, stream>>>(
        user_emb, side32, fcfrag, fc_b, fcg_w, fcg_b, mask8, risky);
    fix_risky_kernel<<<(NUQ * 64 + 255) / 256, 256, 0, stream>>>(
        user_emb, item_emb, fc_w, fc_b, fcg_w, fcg_b,
        row_ofs, edge_cv, risky, mask8);

    // --- layer 1 (needed rows only) ---
    layer1_kernel<<<row_blocks, 256, 0, stream>>>(row_ofs, edge_cv, mask8,
                                                  needed, sideh, emb4);

    // --- fused layer2 + gamma (sampled rows only) ---
    gamma_kernel<<<((size_t)B * 64 + 255) / 256, 256, 0, stream>>>(
        row_ofs, edge_cv, mask8, side32, emb4, users, items, out, B);
}